// Round 1
// baseline (907.204 us; speedup 1.0000x reference)
//
#include <hip/hip_runtime.h>
#include <cstdint>
#include <cstddef>

namespace {

constexpr int kNInv  = 100000;
constexpr int kNFund = 20000;
constexpr int kH     = 128;
constexpr int kE     = 600000;
constexpr int kEL    = 200000;

// ---------------- CSR construction ----------------

__global__ void count_deg(const int* __restrict__ dst, int* __restrict__ deg, int n) {
  int e = blockIdx.x * blockDim.x + threadIdx.x;
  if (e < n) atomicAdd(&deg[dst[e]], 1);
}

// single-block exclusive scan (n up to ~100k): chunk-per-thread + Hillis-Steele
__global__ void scan_excl(const int* __restrict__ deg, int* __restrict__ off, int n) {
  __shared__ int sums[1024];
  const int tid = threadIdx.x;
  const int chunk = (n + 1023) >> 10;
  const int lo = tid * chunk;
  const int hi = min(lo + chunk, n);
  int s = 0;
  for (int i = lo; i < hi; ++i) s += deg[i];
  sums[tid] = s;
  __syncthreads();
  for (int d = 1; d < 1024; d <<= 1) {
    int v = (tid >= d) ? sums[tid - d] : 0;
    __syncthreads();
    if (tid >= d) sums[tid] += v;
    __syncthreads();
  }
  int run = (tid == 0) ? 0 : sums[tid - 1];
  for (int i = lo; i < hi; ++i) { off[i] = run; run += deg[i]; }
  if (tid == 1023) off[n] = sums[1023];
}

__global__ void fill_csr(const int* __restrict__ src, const int* __restrict__ dst,
                         int* __restrict__ cur, int* __restrict__ csr, int n) {
  int e = blockIdx.x * blockDim.x + threadIdx.x;
  if (e < n) {
    int pos = atomicAdd(&cur[dst[e]], 1);
    csr[pos] = src[e];
  }
}

// ---------------- mean aggregation (gather, one wave per dst node) ----------------

template <int D>
__global__ void sage_mean(const float* __restrict__ xsrc, const int* __restrict__ csr,
                          const int* __restrict__ off, float* __restrict__ mean, int ndst) {
  constexpr int F = D / 64;  // floats per lane
  const int wave = (int)((blockIdx.x * blockDim.x + threadIdx.x) >> 6);
  const int lane = threadIdx.x & 63;
  if (wave >= ndst) return;
  const int lo = off[wave], hi = off[wave + 1];
  float acc[F];
#pragma unroll
  for (int f = 0; f < F; ++f) acc[f] = 0.f;
  for (int e = lo; e < hi; ++e) {
    const int s = csr[e];
    const float* row = xsrc + (size_t)s * D + lane * F;
#pragma unroll
    for (int f = 0; f < F; ++f) acc[f] += row[f];
  }
  const float sc = (hi > lo) ? 1.0f / (float)(hi - lo) : 0.0f;
  float* o = mean + (size_t)wave * D + lane * F;
#pragma unroll
  for (int f = 0; f < F; ++f) o[f] = acc[f] * sc;
}

// ---------------- fused SAGE linear: out = act(A1@W1^T + A2@W2^T + bias) ----------------
// A1:[n,d1], A2:[n,d2] (optional), W1:[128 rows, stride ldw1], W2:[128, ldw2], out:[n,128].
// Block: 256 threads -> 32 rows x 128 cols tile, 4x4 register blocking.
__global__ __launch_bounds__(256) void fused_gemm(
    const float* __restrict__ A1, int d1,
    const float* __restrict__ A2, int d2,
    const float* __restrict__ W1, int ldw1,
    const float* __restrict__ W2, int ldw2,
    const float* __restrict__ bias, int act,
    float* __restrict__ out, int n)
{
  __shared__ float lds_a[32][36];   // [kk][r], row stride 144B (16B-aligned)
  __shared__ float lds_w[32][128];  // [kk][h]
  const int tid = threadIdx.x;
  const int row0 = blockIdx.x * 32;
  const int tc = tid & 31;   // col group -> cols tc*4..tc*4+3
  const int tr = tid >> 5;   // row group -> rows tr*4..tr*4+3
  float acc[4][4] = {{0.f, 0.f, 0.f, 0.f}};

  for (int seg = 0; seg < 2; ++seg) {
    const float* A = seg ? A2 : A1;
    const float* W = seg ? W2 : W1;
    const int d = seg ? d2 : d1;
    const int ldw = seg ? ldw2 : ldw1;
    if (d == 0) continue;
    for (int k0 = 0; k0 < d; k0 += 32) {
      // stage A chunk transposed: lds_a[kk][r] = A[row0+r][k0+kk]
      {
        const int r = tid >> 3;          // 0..31
        const int kk = (tid & 7) << 2;   // 0,4,..,28
        float4 v = *(const float4*)(A + (size_t)(row0 + r) * d + k0 + kk);
        lds_a[kk + 0][r] = v.x;
        lds_a[kk + 1][r] = v.y;
        lds_a[kk + 2][r] = v.z;
        lds_a[kk + 3][r] = v.w;
      }
      // stage W chunk transposed: lds_w[kk][h] = W[h][k0+kk]
      {
        const int h = tid & 127;
        const int kb = (tid >> 7) << 4;  // 0 or 16
        const float* wrow = W + (size_t)h * ldw + k0 + kb;
#pragma unroll
        for (int j = 0; j < 16; j += 4) {
          float4 v = *(const float4*)(wrow + j);
          lds_w[kb + j + 0][h] = v.x;
          lds_w[kb + j + 1][h] = v.y;
          lds_w[kb + j + 2][h] = v.z;
          lds_w[kb + j + 3][h] = v.w;
        }
      }
      __syncthreads();
#pragma unroll
      for (int kk = 0; kk < 32; ++kk) {
        float a4[4], w4[4];
        *(float4*)a4 = *(const float4*)&lds_a[kk][tr << 2];
        *(float4*)w4 = *(const float4*)&lds_w[kk][tc << 2];
#pragma unroll
        for (int i = 0; i < 4; ++i)
#pragma unroll
          for (int j = 0; j < 4; ++j)
            acc[i][j] = fmaf(a4[i], w4[j], acc[i][j]);
      }
      __syncthreads();
    }
  }

#pragma unroll
  for (int i = 0; i < 4; ++i) {
    const int r = row0 + (tr << 2) + i;
    float tmp[4];
#pragma unroll
    for (int j = 0; j < 4; ++j) {
      float x = acc[i][j];
      if (bias) x += bias[(tc << 2) + j];
      if (act) x = fmaxf(x, 0.f);
      tmp[j] = x;
    }
    *(float4*)(out + (size_t)r * kH + (tc << 2)) = *(const float4*)tmp;
  }
}

// ---------------- link predictor: sigmoid(relu(u_inv[i]+u_fund[j]) . w2 + b2) ----------------

__global__ void link_pred(const float* __restrict__ u_inv, const float* __restrict__ u_fund,
                          const int* __restrict__ ei, const int* __restrict__ ej,
                          const float* __restrict__ Wp2, const float* __restrict__ bp2,
                          float* __restrict__ out, int nl) {
  const int wave = (int)((blockIdx.x * blockDim.x + threadIdx.x) >> 6);
  const int lane = threadIdx.x & 63;
  if (wave >= nl) return;
  const int i = ei[wave];
  const int j = ej[wave];
  float2 a = *(const float2*)(u_inv + (size_t)i * 128 + lane * 2);
  float2 b = *(const float2*)(u_fund + (size_t)j * 128 + lane * 2);
  float v0 = fmaxf(a.x + b.x, 0.f);
  float v1 = fmaxf(a.y + b.y, 0.f);
  float p = v0 * Wp2[lane * 2] + v1 * Wp2[lane * 2 + 1];
#pragma unroll
  for (int o = 32; o > 0; o >>= 1) p += __shfl_xor(p, o);
  if (lane == 0) out[wave] = 1.0f / (1.0f + expf(-(p + bp2[0])));
}

}  // namespace

extern "C" void kernel_launch(void* const* d_in, const int* in_sizes, int n_in,
                              void* d_out, int out_size, void* d_ws, size_t ws_size,
                              hipStream_t stream) {
  const float* x_inv  = (const float*)d_in[0];
  const float* x_fund = (const float*)d_in[1];
  const int* src_if   = (const int*)d_in[2];
  const int* dst_if   = (const int*)d_in[3];
  const int* src_fi   = (const int*)d_in[4];
  const int* dst_fi   = (const int*)d_in[5];
  const int* eli_inv  = (const int*)d_in[6];
  const int* eli_fund = (const int*)d_in[7];
  const float* W1l_if = (const float*)d_in[8];
  const float* b1_if  = (const float*)d_in[9];
  const float* W1r_if = (const float*)d_in[10];
  const float* W1l_fi = (const float*)d_in[11];
  const float* b1_fi  = (const float*)d_in[12];
  const float* W1r_fi = (const float*)d_in[13];
  const float* W2l_if = (const float*)d_in[14];
  const float* b2_if  = (const float*)d_in[15];
  const float* W2r_if = (const float*)d_in[16];
  const float* W2l_fi = (const float*)d_in[17];
  const float* b2_fi  = (const float*)d_in[18];
  const float* W2r_fi = (const float*)d_in[19];
  const float* Wp1    = (const float*)d_in[20];
  const float* bp1    = (const float*)d_in[21];
  const float* Wp2    = (const float*)d_in[22];
  const float* bp2    = (const float*)d_in[23];
  float* out = (float*)d_out;

  char* p = (char*)d_ws;
  auto alloc = [&](size_t bytes) -> void* {
    void* r = (void*)p;
    p += (bytes + 255) & ~(size_t)255;
    return r;
  };
  int* deg_fund = (int*)alloc((size_t)kNFund * 4);
  int* deg_inv  = (int*)alloc((size_t)kNInv * 4);
  int* off_fund = (int*)alloc((size_t)(kNFund + 1) * 4);
  int* off_inv  = (int*)alloc((size_t)(kNInv + 1) * 4);
  int* cur_fund = (int*)alloc((size_t)kNFund * 4);
  int* cur_inv  = (int*)alloc((size_t)kNInv * 4);
  int* csr_if   = (int*)alloc((size_t)kE * 4);
  int* csr_fi   = (int*)alloc((size_t)kE * 4);
  float* bufA = (float*)alloc((size_t)kNFund * 128 * 4);  // mean_fund -> u_fund
  float* bufB = (float*)alloc((size_t)kNFund * 128 * 4);  // h_fund
  float* bufC = (float*)alloc((size_t)kNInv * 128 * 4);   // mean_inv -> u_inv
  float* bufD = (float*)alloc((size_t)kNInv * 128 * 4);   // h_inv
  float* bufE = (float*)alloc((size_t)kNFund * 128 * 4);  // z_fund
  float* bufF = (float*)alloc((size_t)kNInv * 128 * 4);   // z_inv

  hipMemsetAsync(deg_fund, 0, (size_t)kNFund * 4, stream);
  hipMemsetAsync(deg_inv, 0, (size_t)kNInv * 4, stream);

  const int TB = 256;
  const int gE = (kE + TB - 1) / TB;
  count_deg<<<gE, TB, 0, stream>>>(dst_if, deg_fund, kE);
  count_deg<<<gE, TB, 0, stream>>>(dst_fi, deg_inv, kE);
  scan_excl<<<1, 1024, 0, stream>>>(deg_fund, off_fund, kNFund);
  scan_excl<<<1, 1024, 0, stream>>>(deg_inv, off_inv, kNInv);
  hipMemcpyAsync(cur_fund, off_fund, (size_t)kNFund * 4, hipMemcpyDeviceToDevice, stream);
  hipMemcpyAsync(cur_inv, off_inv, (size_t)kNInv * 4, hipMemcpyDeviceToDevice, stream);
  fill_csr<<<gE, TB, 0, stream>>>(src_if, dst_if, cur_fund, csr_if, kE);
  fill_csr<<<gE, TB, 0, stream>>>(src_fi, dst_fi, cur_inv, csr_fi, kE);

  // ---- layer 1 ----
  sage_mean<128><<<(kNFund + 3) / 4, 256, 0, stream>>>(x_inv, csr_if, off_fund, bufA, kNFund);
  fused_gemm<<<kNFund / 32, 256, 0, stream>>>(bufA, 128, x_fund, 64, W1l_if, 128, W1r_if, 64,
                                              b1_if, 1, bufB, kNFund);
  sage_mean<64><<<(kNInv + 3) / 4, 256, 0, stream>>>(x_fund, csr_fi, off_inv, bufC, kNInv);
  fused_gemm<<<kNInv / 32, 256, 0, stream>>>(bufC, 64, x_inv, 128, W1l_fi, 64, W1r_fi, 128,
                                             b1_fi, 1, bufD, kNInv);
  // ---- layer 2 ----
  sage_mean<128><<<(kNFund + 3) / 4, 256, 0, stream>>>(bufD, csr_if, off_fund, bufA, kNFund);
  fused_gemm<<<kNFund / 32, 256, 0, stream>>>(bufA, 128, bufB, 128, W2l_if, 128, W2r_if, 128,
                                              b2_if, 0, bufE, kNFund);
  sage_mean<128><<<(kNInv + 3) / 4, 256, 0, stream>>>(bufB, csr_fi, off_inv, bufC, kNInv);
  fused_gemm<<<kNInv / 32, 256, 0, stream>>>(bufC, 128, bufD, 128, W2l_fi, 128, W2r_fi, 128,
                                             b2_fi, 0, bufF, kNInv);
  // ---- link predictor precompute: u = z @ Wp1_half^T ----
  fused_gemm<<<kNInv / 32, 256, 0, stream>>>(bufF, 128, nullptr, 0, Wp1, 256, nullptr, 0,
                                             nullptr, 0, bufC, kNInv);
  fused_gemm<<<kNFund / 32, 256, 0, stream>>>(bufE, 128, nullptr, 0, Wp1 + 128, 256, nullptr, 0,
                                              bp1, 0, bufA, kNFund);
  // ---- per-link: sigmoid(relu(u_i + u_j) . w + b) ----
  link_pred<<<kEL / 4, 256, 0, stream>>>(bufC, bufA, eli_inv, eli_fund, Wp2, bp2, out, kEL);
}

// Round 2
// 740.005 us; speedup vs baseline: 1.2259x; 1.2259x over previous
//
#include <hip/hip_runtime.h>
#include <cstdint>
#include <cstddef>

namespace {

constexpr int kNInv  = 100000;
constexpr int kNFund = 20000;
constexpr int kH     = 128;
constexpr int kE     = 600000;
constexpr int kEL    = 200000;

// ---------------- CSR construction ----------------

__global__ void count_deg(const int* __restrict__ dst, int* __restrict__ deg, int n) {
  int e = blockIdx.x * blockDim.x + threadIdx.x;
  if (e < n) atomicAdd(&deg[dst[e]], 1);
}

// ---------------- two-level exclusive scan (1024 elems per block) ----------------

__global__ void scan_partial(const int* __restrict__ deg, int* __restrict__ bsum, int n) {
  __shared__ int red[256];
  const int tid = threadIdx.x;
  const int base = blockIdx.x * 1024 + tid * 4;
  int s = 0;
  if (base + 3 < n) {
    int4 v = *(const int4*)(deg + base);
    s = v.x + v.y + v.z + v.w;
  } else {
    for (int i = 0; i < 4; ++i)
      if (base + i < n) s += deg[base + i];
  }
  red[tid] = s;
  __syncthreads();
  for (int d = 128; d > 0; d >>= 1) {
    if (tid < d) red[tid] += red[tid + d];
    __syncthreads();
  }
  if (tid == 0) bsum[blockIdx.x] = red[0];
}

// in-place exclusive scan of bsum[0..nb), nb <= 1024, single block of 1024
__global__ void scan_small(int* __restrict__ bsum, int nb) {
  __shared__ int sh[1024];
  const int tid = threadIdx.x;
  const int v = (tid < nb) ? bsum[tid] : 0;
  sh[tid] = v;
  __syncthreads();
  for (int d = 1; d < 1024; d <<= 1) {
    int t = (tid >= d) ? sh[tid - d] : 0;
    __syncthreads();
    sh[tid] += t;
    __syncthreads();
  }
  if (tid < nb) bsum[tid] = sh[tid] - v;  // exclusive
}

// per-block local exclusive scan + block offset; writes off[0..n], cur[0..n)
__global__ void scan_apply(const int* __restrict__ deg, const int* __restrict__ bsum,
                           int* __restrict__ off, int* __restrict__ cur, int n) {
  __shared__ int red[256];
  const int tid = threadIdx.x;
  const int base = blockIdx.x * 1024 + tid * 4;
  int v[4] = {0, 0, 0, 0};
  const bool full = (base + 3 < n);
  if (full) {
    int4 t = *(const int4*)(deg + base);
    v[0] = t.x; v[1] = t.y; v[2] = t.z; v[3] = t.w;
  } else {
    for (int i = 0; i < 4; ++i)
      if (base + i < n) v[i] = deg[base + i];
  }
  const int s = v[0] + v[1] + v[2] + v[3];
  red[tid] = s;
  __syncthreads();
  for (int d = 1; d < 256; d <<= 1) {
    int t = (tid >= d) ? red[tid - d] : 0;
    __syncthreads();
    red[tid] += t;
    __syncthreads();
  }
  int o[4];
  o[0] = bsum[blockIdx.x] + red[tid] - s;  // exclusive prefix
  o[1] = o[0] + v[0];
  o[2] = o[1] + v[1];
  o[3] = o[2] + v[2];
  if (full) {
    *(int4*)(off + base) = make_int4(o[0], o[1], o[2], o[3]);
    *(int4*)(cur + base) = make_int4(o[0], o[1], o[2], o[3]);
  } else {
    for (int i = 0; i < 4; ++i)
      if (base + i < n) { off[base + i] = o[i]; cur[base + i] = o[i]; }
  }
#pragma unroll
  for (int i = 0; i < 4; ++i)
    if (base + i == n - 1) off[n] = o[i] + v[i];
}

__global__ void fill_csr(const int* __restrict__ src, const int* __restrict__ dst,
                         int* __restrict__ cur, int* __restrict__ csr, int n) {
  int e = blockIdx.x * blockDim.x + threadIdx.x;
  if (e < n) {
    int pos = atomicAdd(&cur[dst[e]], 1);
    csr[pos] = src[e];
  }
}

// ---------------- mean aggregation (gather, one wave per dst node) ----------------

template <int D>
__global__ void sage_mean(const float* __restrict__ xsrc, const int* __restrict__ csr,
                          const int* __restrict__ off, float* __restrict__ mean, int ndst) {
  constexpr int F = D / 64;  // floats per lane
  const int wave = (int)((blockIdx.x * blockDim.x + threadIdx.x) >> 6);
  const int lane = threadIdx.x & 63;
  if (wave >= ndst) return;
  const int lo = off[wave], hi = off[wave + 1];
  float acc[F];
#pragma unroll
  for (int f = 0; f < F; ++f) acc[f] = 0.f;
  for (int e = lo; e < hi; ++e) {
    const int s = csr[e];
    const float* row = xsrc + (size_t)s * D + lane * F;
#pragma unroll
    for (int f = 0; f < F; ++f) acc[f] += row[f];
  }
  const float sc = (hi > lo) ? 1.0f / (float)(hi - lo) : 0.0f;
  float* o = mean + (size_t)wave * D + lane * F;
#pragma unroll
  for (int f = 0; f < F; ++f) o[f] = acc[f] * sc;
}

// ---------------- fused SAGE linear: out = act(A1@W1^T + A2@W2^T + bias) ----------------
// A1:[n,d1], A2:[n,d2] (optional), W1:[128 rows, stride ldw1], W2:[128, ldw2], out:[n,128].
// Block: 256 threads -> 32 rows x 128 cols tile, 4x4 register blocking.
__global__ __launch_bounds__(256) void fused_gemm(
    const float* __restrict__ A1, int d1,
    const float* __restrict__ A2, int d2,
    const float* __restrict__ W1, int ldw1,
    const float* __restrict__ W2, int ldw2,
    const float* __restrict__ bias, int act,
    float* __restrict__ out, int n)
{
  __shared__ float lds_a[32][36];   // [kk][r], row stride 144B (16B-aligned)
  __shared__ float lds_w[32][128];  // [kk][h]
  const int tid = threadIdx.x;
  const int row0 = blockIdx.x * 32;
  const int tc = tid & 31;   // col group -> cols tc*4..tc*4+3
  const int tr = tid >> 5;   // row group -> rows tr*4..tr*4+3
  float acc[4][4] = {{0.f, 0.f, 0.f, 0.f}};

  for (int seg = 0; seg < 2; ++seg) {
    const float* A = seg ? A2 : A1;
    const float* W = seg ? W2 : W1;
    const int d = seg ? d2 : d1;
    const int ldw = seg ? ldw2 : ldw1;
    if (d == 0) continue;
    for (int k0 = 0; k0 < d; k0 += 32) {
      // stage A chunk transposed: lds_a[kk][r] = A[row0+r][k0+kk]
      {
        const int r = tid >> 3;          // 0..31
        const int kk = (tid & 7) << 2;   // 0,4,..,28
        float4 v = *(const float4*)(A + (size_t)(row0 + r) * d + k0 + kk);
        lds_a[kk + 0][r] = v.x;
        lds_a[kk + 1][r] = v.y;
        lds_a[kk + 2][r] = v.z;
        lds_a[kk + 3][r] = v.w;
      }
      // stage W chunk transposed: lds_w[kk][h] = W[h][k0+kk]
      {
        const int h = tid & 127;
        const int kb = (tid >> 7) << 4;  // 0 or 16
        const float* wrow = W + (size_t)h * ldw + k0 + kb;
#pragma unroll
        for (int j = 0; j < 16; j += 4) {
          float4 v = *(const float4*)(wrow + j);
          lds_w[kb + j + 0][h] = v.x;
          lds_w[kb + j + 1][h] = v.y;
          lds_w[kb + j + 2][h] = v.z;
          lds_w[kb + j + 3][h] = v.w;
        }
      }
      __syncthreads();
#pragma unroll
      for (int kk = 0; kk < 32; ++kk) {
        float a4[4], w4[4];
        *(float4*)a4 = *(const float4*)&lds_a[kk][tr << 2];
        *(float4*)w4 = *(const float4*)&lds_w[kk][tc << 2];
#pragma unroll
        for (int i = 0; i < 4; ++i)
#pragma unroll
          for (int j = 0; j < 4; ++j)
            acc[i][j] = fmaf(a4[i], w4[j], acc[i][j]);
      }
      __syncthreads();
    }
  }

#pragma unroll
  for (int i = 0; i < 4; ++i) {
    const int r = row0 + (tr << 2) + i;
    float tmp[4];
#pragma unroll
    for (int j = 0; j < 4; ++j) {
      float x = acc[i][j];
      if (bias) x += bias[(tc << 2) + j];
      if (act) x = fmaxf(x, 0.f);
      tmp[j] = x;
    }
    *(float4*)(out + (size_t)r * kH + (tc << 2)) = *(const float4*)tmp;
  }
}

// ---------------- link predictor: sigmoid(relu(u_inv[i]+u_fund[j]) . w2 + b2) ----------------

__global__ void link_pred(const float* __restrict__ u_inv, const float* __restrict__ u_fund,
                          const int* __restrict__ ei, const int* __restrict__ ej,
                          const float* __restrict__ Wp2, const float* __restrict__ bp2,
                          float* __restrict__ out, int nl) {
  const int wave = (int)((blockIdx.x * blockDim.x + threadIdx.x) >> 6);
  const int lane = threadIdx.x & 63;
  if (wave >= nl) return;
  const int i = ei[wave];
  const int j = ej[wave];
  float2 a = *(const float2*)(u_inv + (size_t)i * 128 + lane * 2);
  float2 b = *(const float2*)(u_fund + (size_t)j * 128 + lane * 2);
  float v0 = fmaxf(a.x + b.x, 0.f);
  float v1 = fmaxf(a.y + b.y, 0.f);
  float p = v0 * Wp2[lane * 2] + v1 * Wp2[lane * 2 + 1];
#pragma unroll
  for (int o = 32; o > 0; o >>= 1) p += __shfl_xor(p, o);
  if (lane == 0) out[wave] = 1.0f / (1.0f + expf(-(p + bp2[0])));
}

}  // namespace

extern "C" void kernel_launch(void* const* d_in, const int* in_sizes, int n_in,
                              void* d_out, int out_size, void* d_ws, size_t ws_size,
                              hipStream_t stream) {
  const float* x_inv  = (const float*)d_in[0];
  const float* x_fund = (const float*)d_in[1];
  const int* src_if   = (const int*)d_in[2];
  const int* dst_if   = (const int*)d_in[3];
  const int* src_fi   = (const int*)d_in[4];
  const int* dst_fi   = (const int*)d_in[5];
  const int* eli_inv  = (const int*)d_in[6];
  const int* eli_fund = (const int*)d_in[7];
  const float* W1l_if = (const float*)d_in[8];
  const float* b1_if  = (const float*)d_in[9];
  const float* W1r_if = (const float*)d_in[10];
  const float* W1l_fi = (const float*)d_in[11];
  const float* b1_fi  = (const float*)d_in[12];
  const float* W1r_fi = (const float*)d_in[13];
  const float* W2l_if = (const float*)d_in[14];
  const float* b2_if  = (const float*)d_in[15];
  const float* W2r_if = (const float*)d_in[16];
  const float* W2l_fi = (const float*)d_in[17];
  const float* b2_fi  = (const float*)d_in[18];
  const float* W2r_fi = (const float*)d_in[19];
  const float* Wp1    = (const float*)d_in[20];
  const float* bp1    = (const float*)d_in[21];
  const float* Wp2    = (const float*)d_in[22];
  const float* bp2    = (const float*)d_in[23];
  float* out = (float*)d_out;

  char* p = (char*)d_ws;
  auto alloc = [&](size_t bytes) -> void* {
    void* r = (void*)p;
    p += (bytes + 255) & ~(size_t)255;
    return r;
  };
  int* deg_fund = (int*)alloc((size_t)kNFund * 4);
  int* deg_inv  = (int*)alloc((size_t)kNInv * 4);
  int* off_fund = (int*)alloc((size_t)(kNFund + 1) * 4);
  int* off_inv  = (int*)alloc((size_t)(kNInv + 1) * 4);
  int* cur_fund = (int*)alloc((size_t)kNFund * 4);
  int* cur_inv  = (int*)alloc((size_t)kNInv * 4);
  int* bsum_fund = (int*)alloc((size_t)1024 * 4);
  int* bsum_inv  = (int*)alloc((size_t)1024 * 4);
  int* csr_if   = (int*)alloc((size_t)kE * 4);
  int* csr_fi   = (int*)alloc((size_t)kE * 4);
  float* bufA = (float*)alloc((size_t)kNFund * 128 * 4);  // mean_fund -> u_fund
  float* bufB = (float*)alloc((size_t)kNFund * 128 * 4);  // h_fund
  float* bufC = (float*)alloc((size_t)kNInv * 128 * 4);   // mean_inv -> u_inv
  float* bufD = (float*)alloc((size_t)kNInv * 128 * 4);   // h_inv
  float* bufE = (float*)alloc((size_t)kNFund * 128 * 4);  // z_fund
  float* bufF = (float*)alloc((size_t)kNInv * 128 * 4);   // z_inv

  hipMemsetAsync(deg_fund, 0, (size_t)kNFund * 4, stream);
  hipMemsetAsync(deg_inv, 0, (size_t)kNInv * 4, stream);

  const int TB = 256;
  const int gE = (kE + TB - 1) / TB;
  const int nbFund = (kNFund + 1023) / 1024;  // 20
  const int nbInv  = (kNInv + 1023) / 1024;   // 98

  count_deg<<<gE, TB, 0, stream>>>(dst_if, deg_fund, kE);
  count_deg<<<gE, TB, 0, stream>>>(dst_fi, deg_inv, kE);
  scan_partial<<<nbFund, 256, 0, stream>>>(deg_fund, bsum_fund, kNFund);
  scan_partial<<<nbInv, 256, 0, stream>>>(deg_inv, bsum_inv, kNInv);
  scan_small<<<1, 1024, 0, stream>>>(bsum_fund, nbFund);
  scan_small<<<1, 1024, 0, stream>>>(bsum_inv, nbInv);
  scan_apply<<<nbFund, 256, 0, stream>>>(deg_fund, bsum_fund, off_fund, cur_fund, kNFund);
  scan_apply<<<nbInv, 256, 0, stream>>>(deg_inv, bsum_inv, off_inv, cur_inv, kNInv);
  fill_csr<<<gE, TB, 0, stream>>>(src_if, dst_if, cur_fund, csr_if, kE);
  fill_csr<<<gE, TB, 0, stream>>>(src_fi, dst_fi, cur_inv, csr_fi, kE);

  // ---- layer 1 ----
  sage_mean<128><<<(kNFund + 3) / 4, 256, 0, stream>>>(x_inv, csr_if, off_fund, bufA, kNFund);
  fused_gemm<<<kNFund / 32, 256, 0, stream>>>(bufA, 128, x_fund, 64, W1l_if, 128, W1r_if, 64,
                                              b1_if, 1, bufB, kNFund);
  sage_mean<64><<<(kNInv + 3) / 4, 256, 0, stream>>>(x_fund, csr_fi, off_inv, bufC, kNInv);
  fused_gemm<<<kNInv / 32, 256, 0, stream>>>(bufC, 64, x_inv, 128, W1l_fi, 64, W1r_fi, 128,
                                             b1_fi, 1, bufD, kNInv);
  // ---- layer 2 ----
  sage_mean<128><<<(kNFund + 3) / 4, 256, 0, stream>>>(bufD, csr_if, off_fund, bufA, kNFund);
  fused_gemm<<<kNFund / 32, 256, 0, stream>>>(bufA, 128, bufB, 128, W2l_if, 128, W2r_if, 128,
                                              b2_if, 0, bufE, kNFund);
  sage_mean<128><<<(kNInv + 3) / 4, 256, 0, stream>>>(bufB, csr_fi, off_inv, bufC, kNInv);
  fused_gemm<<<kNInv / 32, 256, 0, stream>>>(bufC, 128, bufD, 128, W2l_fi, 128, W2r_fi, 128,
                                             b2_fi, 0, bufF, kNInv);
  // ---- link predictor precompute: u = z @ Wp1_half^T ----
  fused_gemm<<<kNInv / 32, 256, 0, stream>>>(bufF, 128, nullptr, 0, Wp1, 256, nullptr, 0,
                                             nullptr, 0, bufC, kNInv);
  fused_gemm<<<kNFund / 32, 256, 0, stream>>>(bufE, 128, nullptr, 0, Wp1 + 128, 256, nullptr, 0,
                                              bp1, 0, bufA, kNFund);
  // ---- per-link: sigmoid(relu(u_i + u_j) . w + b) ----
  link_pred<<<kEL / 4, 256, 0, stream>>>(bufC, bufA, eli_inv, eli_fund, Wp2, bp2, out, kEL);
}

// Round 3
// 589.022 us; speedup vs baseline: 1.5402x; 1.2563x over previous
//
#include <hip/hip_runtime.h>
#include <cstdint>
#include <cstddef>

namespace {

typedef short bf16x8 __attribute__((ext_vector_type(8)));
typedef float f32x4 __attribute__((ext_vector_type(4)));

constexpr int kNInv  = 100000;
constexpr int kNFund = 20000;
constexpr int kH     = 128;
constexpr int kE     = 600000;
constexpr int kEL    = 200000;

// weight arena element offsets (bf16 elems)
constexpr int kW1lIF = 0;        // 128x128
constexpr int kW1rIF = 16384;    // 128x64
constexpr int kW1lFI = 24576;    // 128x64
constexpr int kW1rFI = 32768;    // 128x128
constexpr int kW2lIF = 49152;    // 128x128
constexpr int kW2rIF = 65536;    // 128x128
constexpr int kW2lFI = 81920;    // 128x128
constexpr int kW2rFI = 98304;    // 128x128
constexpr int kWp1   = 114688;   // 128x256
constexpr int kWTot  = 147456;

__device__ __forceinline__ float bf_lo(uint32_t u) {
  union { uint32_t i; float f; } v; v.i = u << 16; return v.f;
}
__device__ __forceinline__ float bf_hi(uint32_t u) {
  union { uint32_t i; float f; } v; v.i = u & 0xffff0000u; return v.f;
}
__device__ __forceinline__ float bf1(ushort u) {
  union { uint32_t i; float f; } v; v.i = ((uint32_t)u) << 16; return v.f;
}
__device__ __forceinline__ ushort f2bf(float f) {  // round-nearest-even
  union { float f; uint32_t i; } v; v.f = f;
  uint32_t x = v.i;
  return (ushort)((x + 0x7fffu + ((x >> 16) & 1u)) >> 16);
}

// ---------------- bulk f32 -> bf16 conversion (x_inv, x_fund, all weights) ----------------

constexpr int kXiQ = kNInv * 128 / 4;    // 3,200,000 quads
constexpr int kXfQ = kNFund * 64 / 4;    // 320,000
constexpr int kWQ  = kWTot / 4;          // 36,864
constexpr int kTotQ = kXiQ + kXfQ + kWQ;

__global__ void convert_all(const float* __restrict__ xi, const float* __restrict__ xf,
                            const float* w0, const float* w1, const float* w2, const float* w3,
                            const float* w4, const float* w5, const float* w6, const float* w7,
                            const float* w8,
                            ushort* __restrict__ xi_b, ushort* __restrict__ xf_b,
                            ushort* __restrict__ wa) {
  const int q = blockIdx.x * blockDim.x + threadIdx.x;
  if (q >= kTotQ) return;
  const float* src;
  ushort* dst;
  int sidx, didx;
  if (q < kXiQ) {
    src = xi; dst = xi_b; sidx = q * 4; didx = q * 4;
  } else if (q < kXiQ + kXfQ) {
    src = xf; dst = xf_b; sidx = (q - kXiQ) * 4; didx = sidx;
  } else {
    const int e = (q - kXiQ - kXfQ) * 4;  // elem offset into arena
    const float* ws[9] = {w0, w1, w2, w3, w4, w5, w6, w7, w8};
    const int beg[10] = {kW1lIF, kW1rIF, kW1lFI, kW1rFI, kW2lIF, kW2rIF, kW2lFI, kW2rFI, kWp1, kWTot};
    int s = 0;
    while (e >= beg[s + 1]) ++s;
    src = ws[s]; dst = wa; sidx = e - beg[s]; didx = e;
  }
  float4 v = *(const float4*)(src + sidx);
  ushort4 o = make_ushort4(f2bf(v.x), f2bf(v.y), f2bf(v.z), f2bf(v.w));
  *(ushort4*)(dst + didx) = o;
}

// ---------------- CSR construction ----------------

__global__ void count_deg(const int* __restrict__ dst, int* __restrict__ deg, int n) {
  int e = blockIdx.x * blockDim.x + threadIdx.x;
  if (e < n) atomicAdd(&deg[dst[e]], 1);
}

__global__ void scan_partial(const int* __restrict__ deg, int* __restrict__ bsum, int n) {
  __shared__ int red[256];
  const int tid = threadIdx.x;
  const int base = blockIdx.x * 1024 + tid * 4;
  int s = 0;
  if (base + 3 < n) {
    int4 v = *(const int4*)(deg + base);
    s = v.x + v.y + v.z + v.w;
  } else {
    for (int i = 0; i < 4; ++i)
      if (base + i < n) s += deg[base + i];
  }
  red[tid] = s;
  __syncthreads();
  for (int d = 128; d > 0; d >>= 1) {
    if (tid < d) red[tid] += red[tid + d];
    __syncthreads();
  }
  if (tid == 0) bsum[blockIdx.x] = red[0];
}

__global__ void scan_small(int* __restrict__ bsum, int nb) {
  __shared__ int sh[1024];
  const int tid = threadIdx.x;
  const int v = (tid < nb) ? bsum[tid] : 0;
  sh[tid] = v;
  __syncthreads();
  for (int d = 1; d < 1024; d <<= 1) {
    int t = (tid >= d) ? sh[tid - d] : 0;
    __syncthreads();
    sh[tid] += t;
    __syncthreads();
  }
  if (tid < nb) bsum[tid] = sh[tid] - v;
}

__global__ void scan_apply(const int* __restrict__ deg, const int* __restrict__ bsum,
                           int* __restrict__ off, int* __restrict__ cur, int n) {
  __shared__ int red[256];
  const int tid = threadIdx.x;
  const int base = blockIdx.x * 1024 + tid * 4;
  int v[4] = {0, 0, 0, 0};
  const bool full = (base + 3 < n);
  if (full) {
    int4 t = *(const int4*)(deg + base);
    v[0] = t.x; v[1] = t.y; v[2] = t.z; v[3] = t.w;
  } else {
    for (int i = 0; i < 4; ++i)
      if (base + i < n) v[i] = deg[base + i];
  }
  const int s = v[0] + v[1] + v[2] + v[3];
  red[tid] = s;
  __syncthreads();
  for (int d = 1; d < 256; d <<= 1) {
    int t = (tid >= d) ? red[tid - d] : 0;
    __syncthreads();
    red[tid] += t;
    __syncthreads();
  }
  int o[4];
  o[0] = bsum[blockIdx.x] + red[tid] - s;
  o[1] = o[0] + v[0];
  o[2] = o[1] + v[1];
  o[3] = o[2] + v[2];
  if (full) {
    *(int4*)(off + base) = make_int4(o[0], o[1], o[2], o[3]);
    *(int4*)(cur + base) = make_int4(o[0], o[1], o[2], o[3]);
  } else {
    for (int i = 0; i < 4; ++i)
      if (base + i < n) { off[base + i] = o[i]; cur[base + i] = o[i]; }
  }
#pragma unroll
  for (int i = 0; i < 4; ++i)
    if (base + i == n - 1) off[n] = o[i] + v[i];
}

__global__ void fill_csr(const int* __restrict__ src, const int* __restrict__ dst,
                         int* __restrict__ cur, int* __restrict__ csr, int n) {
  int e = blockIdx.x * blockDim.x + threadIdx.x;
  if (e < n) {
    int pos = atomicAdd(&cur[dst[e]], 1);
    csr[pos] = src[e];
  }
}

// ---------------- mean aggregation over bf16 rows (one wave per dst node) ----------------

template <int D>
__global__ void sage_mean_bf(const ushort* __restrict__ xsrc, const int* __restrict__ csr,
                             const int* __restrict__ off, ushort* __restrict__ mean, int ndst) {
  const int wave = (int)((blockIdx.x * blockDim.x + threadIdx.x) >> 6);
  const int lane = threadIdx.x & 63;
  if (wave >= ndst) return;
  const int lo = off[wave], hi = off[wave + 1];
  if (D == 128) {
    float a0 = 0.f, a1 = 0.f;
    for (int e = lo; e < hi; ++e) {
      const int s = csr[e];
      uint32_t u = *(const uint32_t*)(xsrc + (size_t)s * D + lane * 2);
      a0 += bf_lo(u);
      a1 += bf_hi(u);
    }
    const float sc = (hi > lo) ? 1.0f / (float)(hi - lo) : 0.0f;
    uint32_t o = (uint32_t)f2bf(a0 * sc) | ((uint32_t)f2bf(a1 * sc) << 16);
    *(uint32_t*)(mean + (size_t)wave * D + lane * 2) = o;
  } else {  // D == 64
    float a0 = 0.f;
    for (int e = lo; e < hi; ++e) {
      const int s = csr[e];
      a0 += bf1(xsrc[(size_t)s * D + lane]);
    }
    const float sc = (hi > lo) ? 1.0f / (float)(hi - lo) : 0.0f;
    mean[(size_t)wave * D + lane] = f2bf(a0 * sc);
  }
}

// ---------------- MFMA GEMM: out[n,128] = act(A1@W1^T + A2@W2^T + bias) ----------------
// A row-major bf16 [n,d]; W row-major bf16 [128, ldw]. Per wave: 32 rows x 128 cols.
// mfma(w_frag, a_frag, acc): lane holds out[row0 + rt*16 + (lane&15)][ct*16 + (lane>>4)*4 + j].
__global__ __launch_bounds__(256) void mfma_gemm(
    const ushort* __restrict__ A1, int d1,
    const ushort* __restrict__ A2, int d2,
    const ushort* __restrict__ W1, int ldw1,
    const ushort* __restrict__ W2, int ldw2,
    const float* __restrict__ bias, int act,
    ushort* __restrict__ out, int n)
{
  const int tid = threadIdx.x;
  const int wid = tid >> 6;
  const int lane = tid & 63;
  const int lo16 = lane & 15;
  const int hi4 = lane >> 4;           // 0..3
  const int row0 = blockIdx.x * 128 + wid * 32;

  f32x4 acc[2][8];
#pragma unroll
  for (int rt = 0; rt < 2; ++rt)
#pragma unroll
    for (int ct = 0; ct < 8; ++ct)
      acc[rt][ct] = (f32x4){0.f, 0.f, 0.f, 0.f};

  const int r0 = min(row0 + lo16, n - 1);
  const int r1 = min(row0 + 16 + lo16, n - 1);

#pragma unroll
  for (int seg = 0; seg < 2; ++seg) {
    const ushort* A = seg ? A2 : A1;
    const ushort* W = seg ? W2 : W1;
    const int d = seg ? d2 : d1;
    const int ldw = seg ? ldw2 : ldw1;
    if (d == 0) continue;
    const ushort* a0p = A + (size_t)r0 * d + hi4 * 8;
    const ushort* a1p = A + (size_t)r1 * d + hi4 * 8;
    const ushort* wp = W + (size_t)lo16 * ldw + hi4 * 8;
    for (int k0 = 0; k0 < d; k0 += 32) {
      bf16x8 a0 = *(const bf16x8*)(a0p + k0);
      bf16x8 a1 = *(const bf16x8*)(a1p + k0);
#pragma unroll
      for (int ct = 0; ct < 8; ++ct) {
        bf16x8 w = *(const bf16x8*)(wp + (size_t)ct * 16 * ldw + k0);
        acc[0][ct] = __builtin_amdgcn_mfma_f32_16x16x32_bf16(w, a0, acc[0][ct], 0, 0, 0);
        acc[1][ct] = __builtin_amdgcn_mfma_f32_16x16x32_bf16(w, a1, acc[1][ct], 0, 0, 0);
      }
    }
  }

  const int colb = hi4 * 4;
#pragma unroll
  for (int rt = 0; rt < 2; ++rt) {
    const int row = row0 + rt * 16 + lo16;
    if (row < n) {
#pragma unroll
      for (int ct = 0; ct < 8; ++ct) {
        float b4[4] = {0.f, 0.f, 0.f, 0.f};
        if (bias) *(float4*)b4 = *(const float4*)(bias + ct * 16 + colb);
        ushort o[4];
#pragma unroll
        for (int j = 0; j < 4; ++j) {
          float x = acc[rt][ct][j] + b4[j];
          if (act) x = fmaxf(x, 0.f);
          o[j] = f2bf(x);
        }
        *(ushort4*)(out + (size_t)row * kH + ct * 16 + colb) = *(const ushort4*)o;
      }
    }
  }
}

// ---------------- link predictor: sigmoid(relu(u_inv[i]+u_fund[j]) . w2 + b2) ----------------

__global__ void link_pred(const ushort* __restrict__ u_inv, const ushort* __restrict__ u_fund,
                          const int* __restrict__ ei, const int* __restrict__ ej,
                          const float* __restrict__ Wp2, const float* __restrict__ bp2,
                          float* __restrict__ out, int nl) {
  const int wave = (int)((blockIdx.x * blockDim.x + threadIdx.x) >> 6);
  const int lane = threadIdx.x & 63;
  if (wave >= nl) return;
  const int i = ei[wave];
  const int j = ej[wave];
  uint32_t ua = *(const uint32_t*)(u_inv + (size_t)i * 128 + lane * 2);
  uint32_t ub = *(const uint32_t*)(u_fund + (size_t)j * 128 + lane * 2);
  float v0 = fmaxf(bf_lo(ua) + bf_lo(ub), 0.f);
  float v1 = fmaxf(bf_hi(ua) + bf_hi(ub), 0.f);
  float p = v0 * Wp2[lane * 2] + v1 * Wp2[lane * 2 + 1];
#pragma unroll
  for (int o = 32; o > 0; o >>= 1) p += __shfl_xor(p, o);
  if (lane == 0) out[wave] = 1.0f / (1.0f + expf(-(p + bp2[0])));
}

}  // namespace

extern "C" void kernel_launch(void* const* d_in, const int* in_sizes, int n_in,
                              void* d_out, int out_size, void* d_ws, size_t ws_size,
                              hipStream_t stream) {
  const float* x_inv  = (const float*)d_in[0];
  const float* x_fund = (const float*)d_in[1];
  const int* src_if   = (const int*)d_in[2];
  const int* dst_if   = (const int*)d_in[3];
  const int* src_fi   = (const int*)d_in[4];
  const int* dst_fi   = (const int*)d_in[5];
  const int* eli_inv  = (const int*)d_in[6];
  const int* eli_fund = (const int*)d_in[7];
  const float* W1l_if = (const float*)d_in[8];
  const float* b1_if  = (const float*)d_in[9];
  const float* W1r_if = (const float*)d_in[10];
  const float* W1l_fi = (const float*)d_in[11];
  const float* b1_fi  = (const float*)d_in[12];
  const float* W1r_fi = (const float*)d_in[13];
  const float* W2l_if = (const float*)d_in[14];
  const float* b2_if  = (const float*)d_in[15];
  const float* W2r_if = (const float*)d_in[16];
  const float* W2l_fi = (const float*)d_in[17];
  const float* b2_fi  = (const float*)d_in[18];
  const float* W2r_fi = (const float*)d_in[19];
  const float* Wp1    = (const float*)d_in[20];
  const float* bp1    = (const float*)d_in[21];
  const float* Wp2    = (const float*)d_in[22];
  const float* bp2    = (const float*)d_in[23];
  float* out = (float*)d_out;

  char* p = (char*)d_ws;
  auto alloc = [&](size_t bytes) -> void* {
    void* r = (void*)p;
    p += (bytes + 255) & ~(size_t)255;
    return r;
  };
  int* deg_fund = (int*)alloc((size_t)kNFund * 4);
  int* deg_inv  = (int*)alloc((size_t)kNInv * 4);
  int* off_fund = (int*)alloc((size_t)(kNFund + 1) * 4);
  int* off_inv  = (int*)alloc((size_t)(kNInv + 1) * 4);
  int* cur_fund = (int*)alloc((size_t)kNFund * 4);
  int* cur_inv  = (int*)alloc((size_t)kNInv * 4);
  int* bsum_fund = (int*)alloc((size_t)1024 * 4);
  int* bsum_inv  = (int*)alloc((size_t)1024 * 4);
  int* csr_if   = (int*)alloc((size_t)kE * 4);
  int* csr_fi   = (int*)alloc((size_t)kE * 4);
  ushort* xi_b = (ushort*)alloc((size_t)kNInv * 128 * 2);
  ushort* xf_b = (ushort*)alloc((size_t)kNFund * 64 * 2);
  ushort* wa   = (ushort*)alloc((size_t)kWTot * 2);
  ushort* bufA = (ushort*)alloc((size_t)kNFund * 128 * 2);  // mean_fund -> u_fund
  ushort* bufB = (ushort*)alloc((size_t)kNFund * 128 * 2);  // h_fund
  ushort* bufC = (ushort*)alloc((size_t)kNInv * 128 * 2);   // mean_inv -> u_inv
  ushort* bufD = (ushort*)alloc((size_t)kNInv * 128 * 2);   // h_inv
  ushort* bufE = (ushort*)alloc((size_t)kNFund * 128 * 2);  // z_fund
  ushort* bufF = (ushort*)alloc((size_t)kNInv * 128 * 2);   // z_inv

  hipMemsetAsync(deg_fund, 0, (size_t)kNFund * 4, stream);
  hipMemsetAsync(deg_inv, 0, (size_t)kNInv * 4, stream);

  const int TB = 256;
  const int gE = (kE + TB - 1) / TB;
  const int nbFund = (kNFund + 1023) / 1024;  // 20
  const int nbInv  = (kNInv + 1023) / 1024;   // 98

  convert_all<<<(kTotQ + TB - 1) / TB, TB, 0, stream>>>(
      x_inv, x_fund, W1l_if, W1r_if, W1l_fi, W1r_fi, W2l_if, W2r_if, W2l_fi, W2r_fi, Wp1,
      xi_b, xf_b, wa);

  count_deg<<<gE, TB, 0, stream>>>(dst_if, deg_fund, kE);
  count_deg<<<gE, TB, 0, stream>>>(dst_fi, deg_inv, kE);
  scan_partial<<<nbFund, 256, 0, stream>>>(deg_fund, bsum_fund, kNFund);
  scan_partial<<<nbInv, 256, 0, stream>>>(deg_inv, bsum_inv, kNInv);
  scan_small<<<1, 1024, 0, stream>>>(bsum_fund, nbFund);
  scan_small<<<1, 1024, 0, stream>>>(bsum_inv, nbInv);
  scan_apply<<<nbFund, 256, 0, stream>>>(deg_fund, bsum_fund, off_fund, cur_fund, kNFund);
  scan_apply<<<nbInv, 256, 0, stream>>>(deg_inv, bsum_inv, off_inv, cur_inv, kNInv);
  fill_csr<<<gE, TB, 0, stream>>>(src_if, dst_if, cur_fund, csr_if, kE);
  fill_csr<<<gE, TB, 0, stream>>>(src_fi, dst_fi, cur_inv, csr_fi, kE);

  const int gemmF = (kNFund + 127) / 128;  // 157
  const int gemmI = (kNInv + 127) / 128;   // 782

  // ---- layer 1 ----
  sage_mean_bf<128><<<(kNFund + 3) / 4, 256, 0, stream>>>(xi_b, csr_if, off_fund, bufA, kNFund);
  mfma_gemm<<<gemmF, 256, 0, stream>>>(bufA, 128, xf_b, 64, wa + kW1lIF, 128, wa + kW1rIF, 64,
                                       b1_if, 1, bufB, kNFund);
  sage_mean_bf<64><<<(kNInv + 3) / 4, 256, 0, stream>>>(xf_b, csr_fi, off_inv, bufC, kNInv);
  mfma_gemm<<<gemmI, 256, 0, stream>>>(bufC, 64, xi_b, 128, wa + kW1lFI, 64, wa + kW1rFI, 128,
                                       b1_fi, 1, bufD, kNInv);
  // ---- layer 2 ----
  sage_mean_bf<128><<<(kNFund + 3) / 4, 256, 0, stream>>>(bufD, csr_if, off_fund, bufA, kNFund);
  mfma_gemm<<<gemmF, 256, 0, stream>>>(bufA, 128, bufB, 128, wa + kW2lIF, 128, wa + kW2rIF, 128,
                                       b2_if, 0, bufE, kNFund);
  sage_mean_bf<128><<<(kNInv + 3) / 4, 256, 0, stream>>>(bufB, csr_fi, off_inv, bufC, kNInv);
  mfma_gemm<<<gemmI, 256, 0, stream>>>(bufC, 128, bufD, 128, wa + kW2lFI, 128, wa + kW2rFI, 128,
                                       b2_fi, 0, bufF, kNInv);
  // ---- link predictor precompute: u = z @ Wp1_half^T ----
  mfma_gemm<<<gemmI, 256, 0, stream>>>(bufF, 128, nullptr, 0, wa + kWp1, 256, nullptr, 0,
                                       nullptr, 0, bufC, kNInv);
  mfma_gemm<<<gemmF, 256, 0, stream>>>(bufE, 128, nullptr, 0, wa + kWp1 + 128, 256, nullptr, 0,
                                       bp1, 0, bufA, kNFund);
  // ---- per-link: sigmoid(relu(u_i + u_j) . w + b) ----
  link_pred<<<kEL / 4, 256, 0, stream>>>(bufC, bufA, eli_inv, eli_fund, Wp2, bp2, out, kEL);
}

// Round 4
// 456.938 us; speedup vs baseline: 1.9854x; 1.2891x over previous
//
#include <hip/hip_runtime.h>
#include <cstdint>
#include <cstddef>

namespace {

typedef short bf16x8 __attribute__((ext_vector_type(8)));
typedef float f32x4 __attribute__((ext_vector_type(4)));

constexpr int kNInv  = 100000;
constexpr int kNFund = 20000;
constexpr int kH     = 128;
constexpr int kE     = 600000;
constexpr int kEL    = 200000;

// weight arena element offsets (bf16 elems)
constexpr int kW1lIF = 0;        // 128x128
constexpr int kW1rIF = 16384;    // 128x64
constexpr int kW1lFI = 24576;    // 128x64
constexpr int kW1rFI = 32768;    // 128x128
constexpr int kW2lIF = 49152;    // 128x128
constexpr int kW2rIF = 65536;    // 128x128
constexpr int kW2lFI = 81920;    // 128x128
constexpr int kW2rFI = 98304;    // 128x128
constexpr int kWp1   = 114688;   // 128x256
constexpr int kWTot  = 147456;

__device__ __forceinline__ float bf_lo(uint32_t u) {
  union { uint32_t i; float f; } v; v.i = u << 16; return v.f;
}
__device__ __forceinline__ float bf_hi(uint32_t u) {
  union { uint32_t i; float f; } v; v.i = u & 0xffff0000u; return v.f;
}
__device__ __forceinline__ float bf1(ushort u) {
  union { uint32_t i; float f; } v; v.i = ((uint32_t)u) << 16; return v.f;
}
__device__ __forceinline__ ushort f2bf(float f) {  // round-nearest-even
  union { float f; uint32_t i; } v; v.f = f;
  uint32_t x = v.i;
  return (ushort)((x + 0x7fffu + ((x >> 16) & 1u)) >> 16);
}

// ---------------- bulk f32 -> bf16 conversion (x_inv, x_fund, all weights) ----------------

constexpr int kXiQ = kNInv * 128 / 4;    // 3,200,000 quads
constexpr int kXfQ = kNFund * 64 / 4;    // 320,000
constexpr int kWQ  = kWTot / 4;          // 36,864
constexpr int kTotQ = kXiQ + kXfQ + kWQ;

__global__ void convert_all(const float* __restrict__ xi, const float* __restrict__ xf,
                            const float* w0, const float* w1, const float* w2, const float* w3,
                            const float* w4, const float* w5, const float* w6, const float* w7,
                            const float* w8,
                            ushort* __restrict__ xi_b, ushort* __restrict__ xf_b,
                            ushort* __restrict__ wa) {
  const int q = blockIdx.x * blockDim.x + threadIdx.x;
  if (q >= kTotQ) return;
  const float* src;
  ushort* dst;
  int sidx, didx;
  if (q < kXiQ) {
    src = xi; dst = xi_b; sidx = q * 4; didx = q * 4;
  } else if (q < kXiQ + kXfQ) {
    src = xf; dst = xf_b; sidx = (q - kXiQ) * 4; didx = sidx;
  } else {
    const int e = (q - kXiQ - kXfQ) * 4;  // elem offset into arena
    const float* ws[9] = {w0, w1, w2, w3, w4, w5, w6, w7, w8};
    const int beg[10] = {kW1lIF, kW1rIF, kW1lFI, kW1rFI, kW2lIF, kW2rIF, kW2lFI, kW2rFI, kWp1, kWTot};
    int s = 0;
    while (e >= beg[s + 1]) ++s;
    src = ws[s]; dst = wa; sidx = e - beg[s]; didx = e;
  }
  float4 v = *(const float4*)(src + sidx);
  ushort4 o = make_ushort4(f2bf(v.x), f2bf(v.y), f2bf(v.z), f2bf(v.w));
  *(ushort4*)(dst + didx) = o;
}

// ---------------- CSR construction ----------------

__global__ void count_deg(const int* __restrict__ dst, int* __restrict__ deg, int n) {
  int e = blockIdx.x * blockDim.x + threadIdx.x;
  if (e < n) atomicAdd(&deg[dst[e]], 1);
}

__global__ void scan_partial(const int* __restrict__ deg, int* __restrict__ bsum, int n) {
  __shared__ int red[256];
  const int tid = threadIdx.x;
  const int base = blockIdx.x * 1024 + tid * 4;
  int s = 0;
  if (base + 3 < n) {
    int4 v = *(const int4*)(deg + base);
    s = v.x + v.y + v.z + v.w;
  } else {
    for (int i = 0; i < 4; ++i)
      if (base + i < n) s += deg[base + i];
  }
  red[tid] = s;
  __syncthreads();
  for (int d = 128; d > 0; d >>= 1) {
    if (tid < d) red[tid] += red[tid + d];
    __syncthreads();
  }
  if (tid == 0) bsum[blockIdx.x] = red[0];
}

__global__ void scan_small(int* __restrict__ bsum, int nb) {
  __shared__ int sh[1024];
  const int tid = threadIdx.x;
  const int v = (tid < nb) ? bsum[tid] : 0;
  sh[tid] = v;
  __syncthreads();
  for (int d = 1; d < 1024; d <<= 1) {
    int t = (tid >= d) ? sh[tid - d] : 0;
    __syncthreads();
    sh[tid] += t;
    __syncthreads();
  }
  if (tid < nb) bsum[tid] = sh[tid] - v;
}

__global__ void scan_apply(const int* __restrict__ deg, const int* __restrict__ bsum,
                           int* __restrict__ off, int* __restrict__ cur, int n) {
  __shared__ int red[256];
  const int tid = threadIdx.x;
  const int base = blockIdx.x * 1024 + tid * 4;
  int v[4] = {0, 0, 0, 0};
  const bool full = (base + 3 < n);
  if (full) {
    int4 t = *(const int4*)(deg + base);
    v[0] = t.x; v[1] = t.y; v[2] = t.z; v[3] = t.w;
  } else {
    for (int i = 0; i < 4; ++i)
      if (base + i < n) v[i] = deg[base + i];
  }
  const int s = v[0] + v[1] + v[2] + v[3];
  red[tid] = s;
  __syncthreads();
  for (int d = 1; d < 256; d <<= 1) {
    int t = (tid >= d) ? red[tid - d] : 0;
    __syncthreads();
    red[tid] += t;
    __syncthreads();
  }
  int o[4];
  o[0] = bsum[blockIdx.x] + red[tid] - s;
  o[1] = o[0] + v[0];
  o[2] = o[1] + v[1];
  o[3] = o[2] + v[2];
  if (full) {
    *(int4*)(off + base) = make_int4(o[0], o[1], o[2], o[3]);
    *(int4*)(cur + base) = make_int4(o[0], o[1], o[2], o[3]);
  } else {
    for (int i = 0; i < 4; ++i)
      if (base + i < n) { off[base + i] = o[i]; cur[base + i] = o[i]; }
  }
#pragma unroll
  for (int i = 0; i < 4; ++i)
    if (base + i == n - 1) off[n] = o[i] + v[i];
}

__global__ void fill_csr(const int* __restrict__ src, const int* __restrict__ dst,
                         int* __restrict__ cur, int* __restrict__ csr, int n) {
  int e = blockIdx.x * blockDim.x + threadIdx.x;
  if (e < n) {
    int pos = atomicAdd(&cur[dst[e]], 1);
    csr[pos] = src[e];
  }
}

// ---------------- mean aggregation over bf16 rows ----------------
// One wave per dst node, split into two 32-lane halves; each half owns alternate
// edges with 8B(4 bf16)/4B(2 bf16) per-lane row slices. Manual unroll x4 keeps
// 8 independent row gathers in flight per wave (latency hiding).

template <int D>
__global__ void sage_mean_bf(const ushort* __restrict__ xsrc, const int* __restrict__ csr,
                             const int* __restrict__ off, ushort* __restrict__ mean, int ndst) {
  const int wave = (int)((blockIdx.x * blockDim.x + threadIdx.x) >> 6);
  const int lane = threadIdx.x & 63;
  const int half = lane >> 5;
  const int l32 = lane & 31;
  if (wave >= ndst) return;
  const int lo = off[wave], hi = off[wave + 1];
  if (D == 128) {
    float a0 = 0.f, a1 = 0.f, a2 = 0.f, a3 = 0.f;
    const size_t coff = (size_t)l32 * 4;
    int e = lo + half;
    for (; e + 6 < hi; e += 8) {
      const int s0 = csr[e], s1 = csr[e + 2], s2 = csr[e + 4], s3 = csr[e + 6];
      uint2 u0 = *(const uint2*)(xsrc + (size_t)s0 * D + coff);
      uint2 u1 = *(const uint2*)(xsrc + (size_t)s1 * D + coff);
      uint2 u2 = *(const uint2*)(xsrc + (size_t)s2 * D + coff);
      uint2 u3 = *(const uint2*)(xsrc + (size_t)s3 * D + coff);
      a0 += bf_lo(u0.x) + bf_lo(u1.x) + bf_lo(u2.x) + bf_lo(u3.x);
      a1 += bf_hi(u0.x) + bf_hi(u1.x) + bf_hi(u2.x) + bf_hi(u3.x);
      a2 += bf_lo(u0.y) + bf_lo(u1.y) + bf_lo(u2.y) + bf_lo(u3.y);
      a3 += bf_hi(u0.y) + bf_hi(u1.y) + bf_hi(u2.y) + bf_hi(u3.y);
    }
    for (; e < hi; e += 2) {
      const int s = csr[e];
      uint2 u = *(const uint2*)(xsrc + (size_t)s * D + coff);
      a0 += bf_lo(u.x); a1 += bf_hi(u.x); a2 += bf_lo(u.y); a3 += bf_hi(u.y);
    }
    a0 += __shfl_xor(a0, 32);
    a1 += __shfl_xor(a1, 32);
    a2 += __shfl_xor(a2, 32);
    a3 += __shfl_xor(a3, 32);
    if (half == 0) {
      const float sc = (hi > lo) ? 1.0f / (float)(hi - lo) : 0.0f;
      ushort o[4] = {f2bf(a0 * sc), f2bf(a1 * sc), f2bf(a2 * sc), f2bf(a3 * sc)};
      *(ushort4*)(mean + (size_t)wave * D + coff) = *(const ushort4*)o;
    }
  } else {  // D == 64
    float a0 = 0.f, a1 = 0.f;
    const size_t coff = (size_t)l32 * 2;
    int e = lo + half;
    for (; e + 6 < hi; e += 8) {
      const int s0 = csr[e], s1 = csr[e + 2], s2 = csr[e + 4], s3 = csr[e + 6];
      uint32_t u0 = *(const uint32_t*)(xsrc + (size_t)s0 * D + coff);
      uint32_t u1 = *(const uint32_t*)(xsrc + (size_t)s1 * D + coff);
      uint32_t u2 = *(const uint32_t*)(xsrc + (size_t)s2 * D + coff);
      uint32_t u3 = *(const uint32_t*)(xsrc + (size_t)s3 * D + coff);
      a0 += bf_lo(u0) + bf_lo(u1) + bf_lo(u2) + bf_lo(u3);
      a1 += bf_hi(u0) + bf_hi(u1) + bf_hi(u2) + bf_hi(u3);
    }
    for (; e < hi; e += 2) {
      const int s = csr[e];
      uint32_t u = *(const uint32_t*)(xsrc + (size_t)s * D + coff);
      a0 += bf_lo(u); a1 += bf_hi(u);
    }
    a0 += __shfl_xor(a0, 32);
    a1 += __shfl_xor(a1, 32);
    if (half == 0) {
      const float sc = (hi > lo) ? 1.0f / (float)(hi - lo) : 0.0f;
      uint32_t o = (uint32_t)f2bf(a0 * sc) | ((uint32_t)f2bf(a1 * sc) << 16);
      *(uint32_t*)(mean + (size_t)wave * D + coff) = o;
    }
  }
}

// ---------------- MFMA GEMM: out[n,128] = act(A1@W1^T + A2@W2^T + bias) ----------------
__global__ __launch_bounds__(256) void mfma_gemm(
    const ushort* __restrict__ A1, int d1,
    const ushort* __restrict__ A2, int d2,
    const ushort* __restrict__ W1, int ldw1,
    const ushort* __restrict__ W2, int ldw2,
    const float* __restrict__ bias, int act,
    ushort* __restrict__ out, int n)
{
  const int tid = threadIdx.x;
  const int wid = tid >> 6;
  const int lane = tid & 63;
  const int lo16 = lane & 15;
  const int hi4 = lane >> 4;           // 0..3
  const int row0 = blockIdx.x * 128 + wid * 32;

  f32x4 acc[2][8];
#pragma unroll
  for (int rt = 0; rt < 2; ++rt)
#pragma unroll
    for (int ct = 0; ct < 8; ++ct)
      acc[rt][ct] = (f32x4){0.f, 0.f, 0.f, 0.f};

  const int r0 = min(row0 + lo16, n - 1);
  const int r1 = min(row0 + 16 + lo16, n - 1);

#pragma unroll
  for (int seg = 0; seg < 2; ++seg) {
    const ushort* A = seg ? A2 : A1;
    const ushort* W = seg ? W2 : W1;
    const int d = seg ? d2 : d1;
    const int ldw = seg ? ldw2 : ldw1;
    if (d == 0) continue;
    const ushort* a0p = A + (size_t)r0 * d + hi4 * 8;
    const ushort* a1p = A + (size_t)r1 * d + hi4 * 8;
    const ushort* wp = W + (size_t)lo16 * ldw + hi4 * 8;
    for (int k0 = 0; k0 < d; k0 += 32) {
      bf16x8 a0 = *(const bf16x8*)(a0p + k0);
      bf16x8 a1 = *(const bf16x8*)(a1p + k0);
#pragma unroll
      for (int ct = 0; ct < 8; ++ct) {
        bf16x8 w = *(const bf16x8*)(wp + (size_t)ct * 16 * ldw + k0);
        acc[0][ct] = __builtin_amdgcn_mfma_f32_16x16x32_bf16(w, a0, acc[0][ct], 0, 0, 0);
        acc[1][ct] = __builtin_amdgcn_mfma_f32_16x16x32_bf16(w, a1, acc[1][ct], 0, 0, 0);
      }
    }
  }

  const int colb = hi4 * 4;
#pragma unroll
  for (int rt = 0; rt < 2; ++rt) {
    const int row = row0 + rt * 16 + lo16;
    if (row < n) {
#pragma unroll
      for (int ct = 0; ct < 8; ++ct) {
        float b4[4] = {0.f, 0.f, 0.f, 0.f};
        if (bias) *(float4*)b4 = *(const float4*)(bias + ct * 16 + colb);
        ushort o[4];
#pragma unroll
        for (int j = 0; j < 4; ++j) {
          float x = acc[rt][ct][j] + b4[j];
          if (act) x = fmaxf(x, 0.f);
          o[j] = f2bf(x);
        }
        *(ushort4*)(out + (size_t)row * kH + ct * 16 + colb) = *(const ushort4*)o;
      }
    }
  }
}

// ---------------- link predictor: 2 links per wave (one per 32-lane half) ----------------

__global__ void link_pred(const ushort* __restrict__ u_inv, const ushort* __restrict__ u_fund,
                          const int* __restrict__ ei, const int* __restrict__ ej,
                          const float* __restrict__ Wp2, const float* __restrict__ bp2,
                          float* __restrict__ out, int nl) {
  const int wave = (int)((blockIdx.x * blockDim.x + threadIdx.x) >> 6);
  const int lane = threadIdx.x & 63;
  const int half = lane >> 5;
  const int l32 = lane & 31;
  const int link = wave * 2 + half;
  if (link >= nl) return;
  const int i = ei[link];
  const int j = ej[link];
  uint2 ua = *(const uint2*)(u_inv + (size_t)i * 128 + l32 * 4);
  uint2 ub = *(const uint2*)(u_fund + (size_t)j * 128 + l32 * 4);
  float4 w = *(const float4*)(Wp2 + l32 * 4);
  float p = fmaxf(bf_lo(ua.x) + bf_lo(ub.x), 0.f) * w.x
          + fmaxf(bf_hi(ua.x) + bf_hi(ub.x), 0.f) * w.y
          + fmaxf(bf_lo(ua.y) + bf_lo(ub.y), 0.f) * w.z
          + fmaxf(bf_hi(ua.y) + bf_hi(ub.y), 0.f) * w.w;
#pragma unroll
  for (int o = 16; o > 0; o >>= 1) p += __shfl_xor(p, o);
  if (l32 == 0) out[link] = 1.0f / (1.0f + expf(-(p + bp2[0])));
}

}  // namespace

extern "C" void kernel_launch(void* const* d_in, const int* in_sizes, int n_in,
                              void* d_out, int out_size, void* d_ws, size_t ws_size,
                              hipStream_t stream) {
  const float* x_inv  = (const float*)d_in[0];
  const float* x_fund = (const float*)d_in[1];
  const int* src_if   = (const int*)d_in[2];
  const int* dst_if   = (const int*)d_in[3];
  const int* src_fi   = (const int*)d_in[4];
  const int* dst_fi   = (const int*)d_in[5];
  const int* eli_inv  = (const int*)d_in[6];
  const int* eli_fund = (const int*)d_in[7];
  const float* W1l_if = (const float*)d_in[8];
  const float* b1_if  = (const float*)d_in[9];
  const float* W1r_if = (const float*)d_in[10];
  const float* W1l_fi = (const float*)d_in[11];
  const float* b1_fi  = (const float*)d_in[12];
  const float* W1r_fi = (const float*)d_in[13];
  const float* W2l_if = (const float*)d_in[14];
  const float* b2_if  = (const float*)d_in[15];
  const float* W2r_if = (const float*)d_in[16];
  const float* W2l_fi = (const float*)d_in[17];
  const float* b2_fi  = (const float*)d_in[18];
  const float* W2r_fi = (const float*)d_in[19];
  const float* Wp1    = (const float*)d_in[20];
  const float* bp1    = (const float*)d_in[21];
  const float* Wp2    = (const float*)d_in[22];
  const float* bp2    = (const float*)d_in[23];
  float* out = (float*)d_out;

  char* p = (char*)d_ws;
  auto alloc = [&](size_t bytes) -> void* {
    void* r = (void*)p;
    p += (bytes + 255) & ~(size_t)255;
    return r;
  };
  int* deg_fund = (int*)alloc((size_t)kNFund * 4);
  int* deg_inv  = (int*)alloc((size_t)kNInv * 4);
  int* off_fund = (int*)alloc((size_t)(kNFund + 1) * 4);
  int* off_inv  = (int*)alloc((size_t)(kNInv + 1) * 4);
  int* cur_fund = (int*)alloc((size_t)kNFund * 4);
  int* cur_inv  = (int*)alloc((size_t)kNInv * 4);
  int* bsum_fund = (int*)alloc((size_t)1024 * 4);
  int* bsum_inv  = (int*)alloc((size_t)1024 * 4);
  int* csr_if   = (int*)alloc((size_t)kE * 4);
  int* csr_fi   = (int*)alloc((size_t)kE * 4);
  ushort* xi_b = (ushort*)alloc((size_t)kNInv * 128 * 2);
  ushort* xf_b = (ushort*)alloc((size_t)kNFund * 64 * 2);
  ushort* wa   = (ushort*)alloc((size_t)kWTot * 2);
  ushort* bufA = (ushort*)alloc((size_t)kNFund * 128 * 2);  // mean_fund -> u_fund
  ushort* bufB = (ushort*)alloc((size_t)kNFund * 128 * 2);  // h_fund
  ushort* bufC = (ushort*)alloc((size_t)kNInv * 128 * 2);   // mean_inv -> u_inv
  ushort* bufD = (ushort*)alloc((size_t)kNInv * 128 * 2);   // h_inv
  ushort* bufE = (ushort*)alloc((size_t)kNFund * 128 * 2);  // z_fund
  ushort* bufF = (ushort*)alloc((size_t)kNInv * 128 * 2);   // z_inv

  hipMemsetAsync(deg_fund, 0, (size_t)kNFund * 4, stream);
  hipMemsetAsync(deg_inv, 0, (size_t)kNInv * 4, stream);

  const int TB = 256;
  const int gE = (kE + TB - 1) / TB;
  const int nbFund = (kNFund + 1023) / 1024;  // 20
  const int nbInv  = (kNInv + 1023) / 1024;   // 98

  convert_all<<<(kTotQ + TB - 1) / TB, TB, 0, stream>>>(
      x_inv, x_fund, W1l_if, W1r_if, W1l_fi, W1r_fi, W2l_if, W2r_if, W2l_fi, W2r_fi, Wp1,
      xi_b, xf_b, wa);

  count_deg<<<gE, TB, 0, stream>>>(dst_if, deg_fund, kE);
  count_deg<<<gE, TB, 0, stream>>>(dst_fi, deg_inv, kE);
  scan_partial<<<nbFund, 256, 0, stream>>>(deg_fund, bsum_fund, kNFund);
  scan_partial<<<nbInv, 256, 0, stream>>>(deg_inv, bsum_inv, kNInv);
  scan_small<<<1, 1024, 0, stream>>>(bsum_fund, nbFund);
  scan_small<<<1, 1024, 0, stream>>>(bsum_inv, nbInv);
  scan_apply<<<nbFund, 256, 0, stream>>>(deg_fund, bsum_fund, off_fund, cur_fund, kNFund);
  scan_apply<<<nbInv, 256, 0, stream>>>(deg_inv, bsum_inv, off_inv, cur_inv, kNInv);
  fill_csr<<<gE, TB, 0, stream>>>(src_if, dst_if, cur_fund, csr_if, kE);
  fill_csr<<<gE, TB, 0, stream>>>(src_fi, dst_fi, cur_inv, csr_fi, kE);

  const int gemmF = (kNFund + 127) / 128;  // 157
  const int gemmI = (kNInv + 127) / 128;   // 782

  // ---- layer 1 ----
  sage_mean_bf<128><<<(kNFund + 3) / 4, 256, 0, stream>>>(xi_b, csr_if, off_fund, bufA, kNFund);
  mfma_gemm<<<gemmF, 256, 0, stream>>>(bufA, 128, xf_b, 64, wa + kW1lIF, 128, wa + kW1rIF, 64,
                                       b1_if, 1, bufB, kNFund);
  sage_mean_bf<64><<<(kNInv + 3) / 4, 256, 0, stream>>>(xf_b, csr_fi, off_inv, bufC, kNInv);
  mfma_gemm<<<gemmI, 256, 0, stream>>>(bufC, 64, xi_b, 128, wa + kW1lFI, 64, wa + kW1rFI, 128,
                                       b1_fi, 1, bufD, kNInv);
  // ---- layer 2 ----
  sage_mean_bf<128><<<(kNFund + 3) / 4, 256, 0, stream>>>(bufD, csr_if, off_fund, bufA, kNFund);
  mfma_gemm<<<gemmF, 256, 0, stream>>>(bufA, 128, bufB, 128, wa + kW2lIF, 128, wa + kW2rIF, 128,
                                       b2_if, 0, bufE, kNFund);
  sage_mean_bf<128><<<(kNInv + 3) / 4, 256, 0, stream>>>(bufB, csr_fi, off_inv, bufC, kNInv);
  mfma_gemm<<<gemmI, 256, 0, stream>>>(bufC, 128, bufD, 128, wa + kW2lFI, 128, wa + kW2rFI, 128,
                                       b2_fi, 0, bufF, kNInv);
  // ---- link predictor precompute: u = z @ Wp1_half^T ----
  mfma_gemm<<<gemmI, 256, 0, stream>>>(bufF, 128, nullptr, 0, wa + kWp1, 256, nullptr, 0,
                                       nullptr, 0, bufC, kNInv);
  mfma_gemm<<<gemmF, 256, 0, stream>>>(bufE, 128, nullptr, 0, wa + kWp1 + 128, 256, nullptr, 0,
                                       bp1, 0, bufA, kNFund);
  // ---- per-link: sigmoid(relu(u_i + u_j) . w + b) ----
  link_pred<<<kEL / 8, 256, 0, stream>>>(bufC, bufA, eli_inv, eli_fund, Wp2, bp2, out, kEL);
}

// Round 5
// 403.371 us; speedup vs baseline: 2.2491x; 1.1328x over previous
//
#include <hip/hip_runtime.h>
#include <cstdint>
#include <cstddef>

namespace {

typedef short bf16x8 __attribute__((ext_vector_type(8)));
typedef float f32x4 __attribute__((ext_vector_type(4)));

constexpr int kNInv  = 100000;
constexpr int kNFund = 20000;
constexpr int kH     = 128;
constexpr int kE     = 600000;
constexpr int kEL    = 200000;

// L1 weight arena element offsets (bf16 elems)
constexpr int kW1lIF = 0;        // 128x128
constexpr int kW1rIF = 16384;    // 128x64
constexpr int kW1lFI = 24576;    // 128x64
constexpr int kW1rFI = 32768;    // 128x128
constexpr int kWTot  = 49152;

// composite (layer2 x predictor) arena: 4 x 128x128 bf16
constexpr int kCW2lFI = 0;
constexpr int kCW2rFI = 16384;
constexpr int kCW2lIF = 32768;
constexpr int kCW2rIF = 49152;

__device__ __forceinline__ float bf_lo(uint32_t u) {
  union { uint32_t i; float f; } v; v.i = u << 16; return v.f;
}
__device__ __forceinline__ float bf_hi(uint32_t u) {
  union { uint32_t i; float f; } v; v.i = u & 0xffff0000u; return v.f;
}
__device__ __forceinline__ ushort f2bf(float f) {  // round-nearest-even
  union { float f; uint32_t i; } v; v.f = f;
  uint32_t x = v.i;
  return (ushort)((x + 0x7fffu + ((x >> 16) & 1u)) >> 16);
}

// ---------------- bulk f32 -> bf16 conversion (x_inv, x_fund, L1 weights) ----------------

constexpr int kXiQ = kNInv * 128 / 4;
constexpr int kXfQ = kNFund * 64 / 4;
constexpr int kWQ  = kWTot / 4;
constexpr int kTotQ = kXiQ + kXfQ + kWQ;

__global__ void convert_all(const float* __restrict__ xi, const float* __restrict__ xf,
                            const float* w0, const float* w1, const float* w2, const float* w3,
                            ushort* __restrict__ xi_b, ushort* __restrict__ xf_b,
                            ushort* __restrict__ wa) {
  const int q = blockIdx.x * blockDim.x + threadIdx.x;
  if (q >= kTotQ) return;
  const float* src;
  ushort* dst;
  int sidx, didx;
  if (q < kXiQ) {
    src = xi; dst = xi_b; sidx = q * 4; didx = q * 4;
  } else if (q < kXiQ + kXfQ) {
    src = xf; dst = xf_b; sidx = (q - kXiQ) * 4; didx = sidx;
  } else {
    const int e = (q - kXiQ - kXfQ) * 4;
    const float* ws[4] = {w0, w1, w2, w3};
    const int beg[5] = {kW1lIF, kW1rIF, kW1lFI, kW1rFI, kWTot};
    int s = 0;
    while (e >= beg[s + 1]) ++s;
    src = ws[s]; dst = wa; sidx = e - beg[s]; didx = e;
  }
  float4 v = *(const float4*)(src + sidx);
  ushort4 o = make_ushort4(f2bf(v.x), f2bf(v.y), f2bf(v.z), f2bf(v.w));
  *(ushort4*)(dst + didx) = o;
}

// ---------------- composite weights: cW = Wp_half @ W2 (f32 math, bf16 out) ----------------
// blocks 0..15: matrix m = b>>2 (0:WpL@W2l_fi 1:WpL@W2r_fi 2:WpR@W2l_if 3:WpR@W2r_if),
//   32-row slab rb = (b&3)*32. block 16: bias transforms.
__global__ void make_composite(const float* __restrict__ Wp1,
                               const float* __restrict__ W2l_fi, const float* __restrict__ W2r_fi,
                               const float* __restrict__ W2l_if, const float* __restrict__ W2r_if,
                               const float* __restrict__ b2_fi, const float* __restrict__ b2_if,
                               const float* __restrict__ bp1,
                               ushort* __restrict__ cw, float* __restrict__ bu_inv,
                               float* __restrict__ bu_fund) {
  const int b = blockIdx.x;
  const int tid = threadIdx.x;
  if (b == 16) {
    if (tid < 128) {
      float s = 0.f;
      for (int j = 0; j < 128; ++j) s += Wp1[(size_t)tid * 256 + j] * b2_fi[j];
      bu_inv[tid] = s;
    } else {
      const int o = tid - 128;
      float s = bp1[o];
      for (int j = 0; j < 128; ++j) s += Wp1[(size_t)o * 256 + 128 + j] * b2_if[j];
      bu_fund[o] = s;
    }
    return;
  }
  const int m = b >> 2;
  const int rb = (b & 3) * 32;
  const float* A = Wp1 + (m >= 2 ? 128 : 0);   // [128 rows, stride 256]
  const float* B = (m == 0) ? W2l_fi : (m == 1) ? W2r_fi : (m == 2) ? W2l_if : W2r_if;
  __shared__ float sA[32][132];
  for (int i = tid; i < 32 * 128; i += 256) {
    const int r = i >> 7, c = i & 127;
    sA[r][c] = A[(size_t)(rb + r) * 256 + c];
  }
  __syncthreads();
  const int lr = tid >> 3;
  const int k0 = (tid & 7) * 16;
  float acc[16];
#pragma unroll
  for (int i = 0; i < 16; ++i) acc[i] = 0.f;
  for (int j = 0; j < 128; ++j) {
    const float a = sA[lr][j];
    const float* Brow = B + (size_t)j * 128 + k0;
#pragma unroll
    for (int i = 0; i < 16; i += 4) {
      float4 v = *(const float4*)(Brow + i);
      acc[i] += a * v.x; acc[i + 1] += a * v.y; acc[i + 2] += a * v.z; acc[i + 3] += a * v.w;
    }
  }
  ushort* dst = cw + (size_t)m * 16384 + (size_t)(rb + lr) * 128 + k0;
  ushort ov[16];
#pragma unroll
  for (int i = 0; i < 16; ++i) ov[i] = f2bf(acc[i]);
#pragma unroll
  for (int i = 0; i < 16; i += 4)
    *(ushort4*)(dst + i) = *(const ushort4*)(ov + i);
}

// ---------------- CSR construction ----------------

__global__ void count_deg(const int* __restrict__ dst, int* __restrict__ deg, int n) {
  int e = blockIdx.x * blockDim.x + threadIdx.x;
  if (e < n) atomicAdd(&deg[dst[e]], 1);
}

__global__ void scan_partial(const int* __restrict__ deg, int* __restrict__ bsum, int n) {
  __shared__ int red[256];
  const int tid = threadIdx.x;
  const int base = blockIdx.x * 1024 + tid * 4;
  int s = 0;
  if (base + 3 < n) {
    int4 v = *(const int4*)(deg + base);
    s = v.x + v.y + v.z + v.w;
  } else {
    for (int i = 0; i < 4; ++i)
      if (base + i < n) s += deg[base + i];
  }
  red[tid] = s;
  __syncthreads();
  for (int d = 128; d > 0; d >>= 1) {
    if (tid < d) red[tid] += red[tid + d];
    __syncthreads();
  }
  if (tid == 0) bsum[blockIdx.x] = red[0];
}

__global__ void scan_small(int* __restrict__ bsum, int nb) {
  __shared__ int sh[1024];
  const int tid = threadIdx.x;
  const int v = (tid < nb) ? bsum[tid] : 0;
  sh[tid] = v;
  __syncthreads();
  for (int d = 1; d < 1024; d <<= 1) {
    int t = (tid >= d) ? sh[tid - d] : 0;
    __syncthreads();
    sh[tid] += t;
    __syncthreads();
  }
  if (tid < nb) bsum[tid] = sh[tid] - v;
}

__global__ void scan_apply(const int* __restrict__ deg, const int* __restrict__ bsum,
                           int* __restrict__ off, int* __restrict__ cur, int n) {
  __shared__ int red[256];
  const int tid = threadIdx.x;
  const int base = blockIdx.x * 1024 + tid * 4;
  int v[4] = {0, 0, 0, 0};
  const bool full = (base + 3 < n);
  if (full) {
    int4 t = *(const int4*)(deg + base);
    v[0] = t.x; v[1] = t.y; v[2] = t.z; v[3] = t.w;
  } else {
    for (int i = 0; i < 4; ++i)
      if (base + i < n) v[i] = deg[base + i];
  }
  const int s = v[0] + v[1] + v[2] + v[3];
  red[tid] = s;
  __syncthreads();
  for (int d = 1; d < 256; d <<= 1) {
    int t = (tid >= d) ? red[tid - d] : 0;
    __syncthreads();
    red[tid] += t;
    __syncthreads();
  }
  int o[4];
  o[0] = bsum[blockIdx.x] + red[tid] - s;
  o[1] = o[0] + v[0];
  o[2] = o[1] + v[1];
  o[3] = o[2] + v[2];
  if (full) {
    *(int4*)(off + base) = make_int4(o[0], o[1], o[2], o[3]);
    *(int4*)(cur + base) = make_int4(o[0], o[1], o[2], o[3]);
  } else {
    for (int i = 0; i < 4; ++i)
      if (base + i < n) { off[base + i] = o[i]; cur[base + i] = o[i]; }
  }
#pragma unroll
  for (int i = 0; i < 4; ++i)
    if (base + i == n - 1) off[n] = o[i] + v[i];
}

__global__ void fill_csr(const int* __restrict__ src, const int* __restrict__ dst,
                         int* __restrict__ cur, int* __restrict__ csr, int n) {
  int e = blockIdx.x * blockDim.x + threadIdx.x;
  if (e < n) {
    int pos = atomicAdd(&cur[dst[e]], 1);
    csr[pos] = src[e];
  }
}

// ---------------- mean aggregation over bf16 rows (two 32-lane halves, unroll x4) --------

template <int D>
__global__ void sage_mean_bf(const ushort* __restrict__ xsrc, const int* __restrict__ csr,
                             const int* __restrict__ off, ushort* __restrict__ mean, int ndst) {
  const int wave = (int)((blockIdx.x * blockDim.x + threadIdx.x) >> 6);
  const int lane = threadIdx.x & 63;
  const int half = lane >> 5;
  const int l32 = lane & 31;
  if (wave >= ndst) return;
  const int lo = off[wave], hi = off[wave + 1];
  if (D == 128) {
    float a0 = 0.f, a1 = 0.f, a2 = 0.f, a3 = 0.f;
    const size_t coff = (size_t)l32 * 4;
    int e = lo + half;
    for (; e + 6 < hi; e += 8) {
      const int s0 = csr[e], s1 = csr[e + 2], s2 = csr[e + 4], s3 = csr[e + 6];
      uint2 u0 = *(const uint2*)(xsrc + (size_t)s0 * D + coff);
      uint2 u1 = *(const uint2*)(xsrc + (size_t)s1 * D + coff);
      uint2 u2 = *(const uint2*)(xsrc + (size_t)s2 * D + coff);
      uint2 u3 = *(const uint2*)(xsrc + (size_t)s3 * D + coff);
      a0 += bf_lo(u0.x) + bf_lo(u1.x) + bf_lo(u2.x) + bf_lo(u3.x);
      a1 += bf_hi(u0.x) + bf_hi(u1.x) + bf_hi(u2.x) + bf_hi(u3.x);
      a2 += bf_lo(u0.y) + bf_lo(u1.y) + bf_lo(u2.y) + bf_lo(u3.y);
      a3 += bf_hi(u0.y) + bf_hi(u1.y) + bf_hi(u2.y) + bf_hi(u3.y);
    }
    for (; e < hi; e += 2) {
      const int s = csr[e];
      uint2 u = *(const uint2*)(xsrc + (size_t)s * D + coff);
      a0 += bf_lo(u.x); a1 += bf_hi(u.x); a2 += bf_lo(u.y); a3 += bf_hi(u.y);
    }
    a0 += __shfl_xor(a0, 32);
    a1 += __shfl_xor(a1, 32);
    a2 += __shfl_xor(a2, 32);
    a3 += __shfl_xor(a3, 32);
    if (half == 0) {
      const float sc = (hi > lo) ? 1.0f / (float)(hi - lo) : 0.0f;
      ushort o[4] = {f2bf(a0 * sc), f2bf(a1 * sc), f2bf(a2 * sc), f2bf(a3 * sc)};
      *(ushort4*)(mean + (size_t)wave * D + coff) = *(const ushort4*)o;
    }
  } else {  // D == 64
    float a0 = 0.f, a1 = 0.f;
    const size_t coff = (size_t)l32 * 2;
    int e = lo + half;
    for (; e + 6 < hi; e += 8) {
      const int s0 = csr[e], s1 = csr[e + 2], s2 = csr[e + 4], s3 = csr[e + 6];
      uint32_t u0 = *(const uint32_t*)(xsrc + (size_t)s0 * D + coff);
      uint32_t u1 = *(const uint32_t*)(xsrc + (size_t)s1 * D + coff);
      uint32_t u2 = *(const uint32_t*)(xsrc + (size_t)s2 * D + coff);
      uint32_t u3 = *(const uint32_t*)(xsrc + (size_t)s3 * D + coff);
      a0 += bf_lo(u0) + bf_lo(u1) + bf_lo(u2) + bf_lo(u3);
      a1 += bf_hi(u0) + bf_hi(u1) + bf_hi(u2) + bf_hi(u3);
    }
    for (; e < hi; e += 2) {
      const int s = csr[e];
      uint32_t u = *(const uint32_t*)(xsrc + (size_t)s * D + coff);
      a0 += bf_lo(u); a1 += bf_hi(u);
    }
    a0 += __shfl_xor(a0, 32);
    a1 += __shfl_xor(a1, 32);
    if (half == 0) {
      const float sc = (hi > lo) ? 1.0f / (float)(hi - lo) : 0.0f;
      uint32_t o = (uint32_t)f2bf(a0 * sc) | ((uint32_t)f2bf(a1 * sc) << 16);
      *(uint32_t*)(mean + (size_t)wave * D + coff) = o;
    }
  }
}

// ---------------- MFMA GEMM: out[n,128] = act(A1@W1^T + A2@W2^T + bias) ----------------
// W staged to LDS in fragment-major order (lane-consecutive 16B -> conflict-free reads);
// all A fragments hoisted into registers before the fully-unrolled MFMA loop.
template <int D1, int D2>
__global__ __launch_bounds__(256) void mfma_gemm_lds(
    const ushort* __restrict__ A1, const ushort* __restrict__ A2,
    const ushort* __restrict__ W1, const ushort* __restrict__ W2,  // bf16 [128][D]
    const float* __restrict__ bias, int act,
    ushort* __restrict__ out, int n)
{
  constexpr int K1 = D1 / 32;            // ksteps seg1
  constexpr int K2 = D2 / 32;
  constexpr int CH1 = 128 * D1 / 8;      // 16B chunks seg1
  constexpr int CHT = 128 * (D1 + D2) / 8;
  __shared__ ushort lds[128 * (D1 + D2)];

  const int tid = threadIdx.x;
  const int wid = tid >> 6;
  const int lane = tid & 63;
  const int lo16 = lane & 15;
  const int hi4 = lane >> 4;
  const int row0 = blockIdx.x * 128 + wid * 32;

  const int r0 = min(row0 + lo16, n - 1);
  const int r1 = min(row0 + 16 + lo16, n - 1);

  // hoist all A fragments (independent global loads -> deep MLP)
  bf16x8 aA[2][K1], aB[2][K2];
  {
    const ushort* a0p = A1 + (size_t)r0 * D1 + hi4 * 8;
    const ushort* a1p = A1 + (size_t)r1 * D1 + hi4 * 8;
#pragma unroll
    for (int k = 0; k < K1; ++k) {
      aA[0][k] = *(const bf16x8*)(a0p + k * 32);
      aA[1][k] = *(const bf16x8*)(a1p + k * 32);
    }
    const ushort* b0p = A2 + (size_t)r0 * D2 + hi4 * 8;
    const ushort* b1p = A2 + (size_t)r1 * D2 + hi4 * 8;
#pragma unroll
    for (int k = 0; k < K2; ++k) {
      aB[0][k] = *(const bf16x8*)(b0p + k * 32);
      aB[1][k] = *(const bf16x8*)(b1p + k * 32);
    }
  }

  // stage W1|W2 into LDS, fragment-major: chunk dest = (kstep*8+ct)*64 + hi4*16 + lo16
#pragma unroll
  for (int it = 0; it < CHT / 256; ++it) {
    const int c = it * 256 + tid;
    const int g = c * 8;
    bf16x8 v;
    int dest;
    if (g < 128 * D1) {
      const int row = g / D1, col = g % D1;
      v = *(const bf16x8*)(W1 + g);
      dest = ((col >> 5) * 8 + (row >> 4)) * 64 + (((col >> 3) & 3) << 4) + (row & 15);
    } else {
      const int g2 = g - 128 * D1;
      const int row = g2 / D2, col = g2 % D2;
      v = *(const bf16x8*)(W2 + g2);
      dest = CH1 + ((col >> 5) * 8 + (row >> 4)) * 64 + (((col >> 3) & 3) << 4) + (row & 15);
    }
    *((bf16x8*)lds + dest) = v;
  }
  __syncthreads();

  f32x4 acc[2][8];
#pragma unroll
  for (int rt = 0; rt < 2; ++rt)
#pragma unroll
    for (int ct = 0; ct < 8; ++ct)
      acc[rt][ct] = (f32x4){0.f, 0.f, 0.f, 0.f};

  const bf16x8* fr = (const bf16x8*)lds;
#pragma unroll
  for (int k = 0; k < K1; ++k) {
#pragma unroll
    for (int ct = 0; ct < 8; ++ct) {
      bf16x8 w = fr[(k * 8 + ct) * 64 + lane];
      acc[0][ct] = __builtin_amdgcn_mfma_f32_16x16x32_bf16(w, aA[0][k], acc[0][ct], 0, 0, 0);
      acc[1][ct] = __builtin_amdgcn_mfma_f32_16x16x32_bf16(w, aA[1][k], acc[1][ct], 0, 0, 0);
    }
  }
#pragma unroll
  for (int k = 0; k < K2; ++k) {
#pragma unroll
    for (int ct = 0; ct < 8; ++ct) {
      bf16x8 w = fr[CH1 / 8 * 8 + (k * 8 + ct) * 64 + lane];  // CH1 chunks offset
      acc[0][ct] = __builtin_amdgcn_mfma_f32_16x16x32_bf16(w, aB[0][k], acc[0][ct], 0, 0, 0);
      acc[1][ct] = __builtin_amdgcn_mfma_f32_16x16x32_bf16(w, aB[1][k], acc[1][ct], 0, 0, 0);
    }
  }

  const int colb = hi4 * 4;
#pragma unroll
  for (int rt = 0; rt < 2; ++rt) {
    const int row = row0 + rt * 16 + lo16;
    if (row < n) {
#pragma unroll
      for (int ct = 0; ct < 8; ++ct) {
        float b4[4];
        *(float4*)b4 = *(const float4*)(bias + ct * 16 + colb);
        ushort o[4];
#pragma unroll
        for (int j = 0; j < 4; ++j) {
          float x = acc[rt][ct][j] + b4[j];
          if (act) x = fmaxf(x, 0.f);
          o[j] = f2bf(x);
        }
        *(ushort4*)(out + (size_t)row * kH + ct * 16 + colb) = *(const ushort4*)o;
      }
    }
  }
}

// ---------------- link predictor: 2 links per wave (one per 32-lane half) ----------------

__global__ void link_pred(const ushort* __restrict__ u_inv, const ushort* __restrict__ u_fund,
                          const int* __restrict__ ei, const int* __restrict__ ej,
                          const float* __restrict__ Wp2, const float* __restrict__ bp2,
                          float* __restrict__ out, int nl) {
  const int wave = (int)((blockIdx.x * blockDim.x + threadIdx.x) >> 6);
  const int lane = threadIdx.x & 63;
  const int half = lane >> 5;
  const int l32 = lane & 31;
  const int link = wave * 2 + half;
  if (link >= nl) return;
  const int i = ei[link];
  const int j = ej[link];
  uint2 ua = *(const uint2*)(u_inv + (size_t)i * 128 + l32 * 4);
  uint2 ub = *(const uint2*)(u_fund + (size_t)j * 128 + l32 * 4);
  float4 w = *(const float4*)(Wp2 + l32 * 4);
  float p = fmaxf(bf_lo(ua.x) + bf_lo(ub.x), 0.f) * w.x
          + fmaxf(bf_hi(ua.x) + bf_hi(ub.x), 0.f) * w.y
          + fmaxf(bf_lo(ua.y) + bf_lo(ub.y), 0.f) * w.z
          + fmaxf(bf_hi(ua.y) + bf_hi(ub.y), 0.f) * w.w;
#pragma unroll
  for (int o = 16; o > 0; o >>= 1) p += __shfl_xor(p, o);
  if (l32 == 0) out[link] = 1.0f / (1.0f + expf(-(p + bp2[0])));
}

}  // namespace

extern "C" void kernel_launch(void* const* d_in, const int* in_sizes, int n_in,
                              void* d_out, int out_size, void* d_ws, size_t ws_size,
                              hipStream_t stream) {
  const float* x_inv  = (const float*)d_in[0];
  const float* x_fund = (const float*)d_in[1];
  const int* src_if   = (const int*)d_in[2];
  const int* dst_if   = (const int*)d_in[3];
  const int* src_fi   = (const int*)d_in[4];
  const int* dst_fi   = (const int*)d_in[5];
  const int* eli_inv  = (const int*)d_in[6];
  const int* eli_fund = (const int*)d_in[7];
  const float* W1l_if = (const float*)d_in[8];
  const float* b1_if  = (const float*)d_in[9];
  const float* W1r_if = (const float*)d_in[10];
  const float* W1l_fi = (const float*)d_in[11];
  const float* b1_fi  = (const float*)d_in[12];
  const float* W1r_fi = (const float*)d_in[13];
  const float* W2l_if = (const float*)d_in[14];
  const float* b2_if  = (const float*)d_in[15];
  const float* W2r_if = (const float*)d_in[16];
  const float* W2l_fi = (const float*)d_in[17];
  const float* b2_fi  = (const float*)d_in[18];
  const float* W2r_fi = (const float*)d_in[19];
  const float* Wp1    = (const float*)d_in[20];
  const float* bp1    = (const float*)d_in[21];
  const float* Wp2    = (const float*)d_in[22];
  const float* bp2    = (const float*)d_in[23];
  float* out = (float*)d_out;

  char* p = (char*)d_ws;
  auto alloc = [&](size_t bytes) -> void* {
    void* r = (void*)p;
    p += (bytes + 255) & ~(size_t)255;
    return r;
  };
  int* deg_fund = (int*)alloc((size_t)kNFund * 4);
  int* deg_inv  = (int*)alloc((size_t)kNInv * 4);
  int* off_fund = (int*)alloc((size_t)(kNFund + 1) * 4);
  int* off_inv  = (int*)alloc((size_t)(kNInv + 1) * 4);
  int* cur_fund = (int*)alloc((size_t)kNFund * 4);
  int* cur_inv  = (int*)alloc((size_t)kNInv * 4);
  int* bsum_fund = (int*)alloc((size_t)1024 * 4);
  int* bsum_inv  = (int*)alloc((size_t)1024 * 4);
  int* csr_if   = (int*)alloc((size_t)kE * 4);
  int* csr_fi   = (int*)alloc((size_t)kE * 4);
  ushort* xi_b = (ushort*)alloc((size_t)kNInv * 128 * 2);
  ushort* xf_b = (ushort*)alloc((size_t)kNFund * 64 * 2);
  ushort* wa   = (ushort*)alloc((size_t)kWTot * 2);
  ushort* cw   = (ushort*)alloc((size_t)4 * 16384 * 2);
  float* bu_inv  = (float*)alloc((size_t)128 * 4);
  float* bu_fund = (float*)alloc((size_t)128 * 4);
  ushort* bufA = (ushort*)alloc((size_t)kNFund * 128 * 2);  // mean_fund
  ushort* bufB = (ushort*)alloc((size_t)kNFund * 128 * 2);  // h_fund
  ushort* bufC = (ushort*)alloc((size_t)kNInv * 128 * 2);   // mean_inv
  ushort* bufD = (ushort*)alloc((size_t)kNInv * 128 * 2);   // h_inv
  ushort* bufE = (ushort*)alloc((size_t)kNFund * 128 * 2);  // u_fund
  ushort* bufF = (ushort*)alloc((size_t)kNInv * 128 * 2);   // u_inv

  hipMemsetAsync(deg_fund, 0, (size_t)kNFund * 4, stream);
  hipMemsetAsync(deg_inv, 0, (size_t)kNInv * 4, stream);

  const int TB = 256;
  const int gE = (kE + TB - 1) / TB;
  const int nbFund = (kNFund + 1023) / 1024;
  const int nbInv  = (kNInv + 1023) / 1024;

  convert_all<<<(kTotQ + TB - 1) / TB, TB, 0, stream>>>(
      x_inv, x_fund, W1l_if, W1r_if, W1l_fi, W1r_fi, xi_b, xf_b, wa);
  make_composite<<<17, 256, 0, stream>>>(Wp1, W2l_fi, W2r_fi, W2l_if, W2r_if,
                                         b2_fi, b2_if, bp1, cw, bu_inv, bu_fund);

  count_deg<<<gE, TB, 0, stream>>>(dst_if, deg_fund, kE);
  count_deg<<<gE, TB, 0, stream>>>(dst_fi, deg_inv, kE);
  scan_partial<<<nbFund, 256, 0, stream>>>(deg_fund, bsum_fund, kNFund);
  scan_partial<<<nbInv, 256, 0, stream>>>(deg_inv, bsum_inv, kNInv);
  scan_small<<<1, 1024, 0, stream>>>(bsum_fund, nbFund);
  scan_small<<<1, 1024, 0, stream>>>(bsum_inv, nbInv);
  scan_apply<<<nbFund, 256, 0, stream>>>(deg_fund, bsum_fund, off_fund, cur_fund, kNFund);
  scan_apply<<<nbInv, 256, 0, stream>>>(deg_inv, bsum_inv, off_inv, cur_inv, kNInv);
  fill_csr<<<gE, TB, 0, stream>>>(src_if, dst_if, cur_fund, csr_if, kE);
  fill_csr<<<gE, TB, 0, stream>>>(src_fi, dst_fi, cur_inv, csr_fi, kE);

  const int gemmF = (kNFund + 127) / 128;  // 157
  const int gemmI = (kNInv + 127) / 128;   // 782

  // ---- layer 1 ----
  sage_mean_bf<128><<<(kNFund + 3) / 4, 256, 0, stream>>>(xi_b, csr_if, off_fund, bufA, kNFund);
  mfma_gemm_lds<128, 64><<<gemmF, 256, 0, stream>>>(bufA, xf_b, wa + kW1lIF, wa + kW1rIF,
                                                    b1_if, 1, bufB, kNFund);
  sage_mean_bf<64><<<(kNInv + 3) / 4, 256, 0, stream>>>(xf_b, csr_fi, off_inv, bufC, kNInv);
  mfma_gemm_lds<64, 128><<<gemmI, 256, 0, stream>>>(bufC, xi_b, wa + kW1lFI, wa + kW1rFI,
                                                    b1_fi, 1, bufD, kNInv);
  // ---- layer 2 folded with predictor precompute (composite weights) ----
  sage_mean_bf<128><<<(kNFund + 3) / 4, 256, 0, stream>>>(bufD, csr_if, off_fund, bufA, kNFund);
  mfma_gemm_lds<128, 128><<<gemmF, 256, 0, stream>>>(bufA, bufB, cw + kCW2lIF, cw + kCW2rIF,
                                                     bu_fund, 0, bufE, kNFund);
  sage_mean_bf<128><<<(kNInv + 3) / 4, 256, 0, stream>>>(bufB, csr_fi, off_inv, bufC, kNInv);
  mfma_gemm_lds<128, 128><<<gemmI, 256, 0, stream>>>(bufC, bufD, cw + kCW2lFI, cw + kCW2rFI,
                                                     bu_inv, 0, bufF, kNInv);
  // ---- per-link: sigmoid(relu(u_i + u_j) . w + b) ----
  link_pred<<<kEL / 8, 256, 0, stream>>>(bufF, bufE, eli_inv, eli_fund, Wp2, bp2, out, kEL);
}

// Round 6
// 382.645 us; speedup vs baseline: 2.3709x; 1.0542x over previous
//
#include <hip/hip_runtime.h>
#include <cstdint>
#include <cstddef>

namespace {

typedef short bf16x8 __attribute__((ext_vector_type(8)));
typedef float f32x4 __attribute__((ext_vector_type(4)));

constexpr int kNInv  = 100000;
constexpr int kNFund = 20000;
constexpr int kH     = 128;
constexpr int kE     = 600000;
constexpr int kEL    = 200000;

// L1 weight arena element offsets (bf16 elems)
constexpr int kW1lIF = 0;        // 128x128
constexpr int kW1rIF = 16384;    // 128x64
constexpr int kW1lFI = 24576;    // 128x64
constexpr int kW1rFI = 32768;    // 128x128
constexpr int kWTot  = 49152;

// composite (layer2 x predictor) arena: 4 x 128x128 bf16
constexpr int kCW2lFI = 0;
constexpr int kCW2rFI = 16384;
constexpr int kCW2lIF = 32768;
constexpr int kCW2rIF = 49152;

__device__ __forceinline__ float bf_lo(uint32_t u) {
  union { uint32_t i; float f; } v; v.i = u << 16; return v.f;
}
__device__ __forceinline__ float bf_hi(uint32_t u) {
  union { uint32_t i; float f; } v; v.i = u & 0xffff0000u; return v.f;
}
__device__ __forceinline__ ushort f2bf(float f) {  // round-nearest-even
  union { float f; uint32_t i; } v; v.f = f;
  uint32_t x = v.i;
  return (ushort)((x + 0x7fffu + ((x >> 16) & 1u)) >> 16);
}

// ---------- bulk f32 -> bf16 conversion + deg zeroing (fused) ----------

constexpr int kXiQ = kNInv * 128 / 4;
constexpr int kXfQ = kNFund * 64 / 4;
constexpr int kWQ  = kWTot / 4;
constexpr int kTotQ = kXiQ + kXfQ + kWQ;
constexpr int kZF = kNFund / 4;   // int4 zero chunks
constexpr int kZI = kNInv / 4;
constexpr int kTotQ2 = kTotQ + kZF + kZI;

__global__ void convert_all(const float* __restrict__ xi, const float* __restrict__ xf,
                            const float* w0, const float* w1, const float* w2, const float* w3,
                            ushort* __restrict__ xi_b, ushort* __restrict__ xf_b,
                            ushort* __restrict__ wa,
                            int* __restrict__ deg_fund, int* __restrict__ deg_inv) {
  const int q = blockIdx.x * blockDim.x + threadIdx.x;
  if (q >= kTotQ2) return;
  if (q >= kTotQ) {
    const int z = q - kTotQ;
    if (z < kZF) ((int4*)deg_fund)[z] = make_int4(0, 0, 0, 0);
    else ((int4*)deg_inv)[z - kZF] = make_int4(0, 0, 0, 0);
    return;
  }
  const float* src;
  ushort* dst;
  int sidx, didx;
  if (q < kXiQ) {
    src = xi; dst = xi_b; sidx = q * 4; didx = q * 4;
  } else if (q < kXiQ + kXfQ) {
    src = xf; dst = xf_b; sidx = (q - kXiQ) * 4; didx = sidx;
  } else {
    const int e = (q - kXiQ - kXfQ) * 4;
    const float* ws[4] = {w0, w1, w2, w3};
    const int beg[5] = {kW1lIF, kW1rIF, kW1lFI, kW1rFI, kWTot};
    int s = 0;
    while (e >= beg[s + 1]) ++s;
    src = ws[s]; dst = wa; sidx = e - beg[s]; didx = e;
  }
  float4 v = *(const float4*)(src + sidx);
  ushort4 o = make_ushort4(f2bf(v.x), f2bf(v.y), f2bf(v.z), f2bf(v.w));
  *(ushort4*)(dst + didx) = o;
}

// ---------- composite weights: cW = Wp_half @ W2 (f32 math, bf16 out) ----------

__global__ void make_composite(const float* __restrict__ Wp1,
                               const float* __restrict__ W2l_fi, const float* __restrict__ W2r_fi,
                               const float* __restrict__ W2l_if, const float* __restrict__ W2r_if,
                               const float* __restrict__ b2_fi, const float* __restrict__ b2_if,
                               const float* __restrict__ bp1,
                               ushort* __restrict__ cw, float* __restrict__ bu_inv,
                               float* __restrict__ bu_fund) {
  const int b = blockIdx.x;
  const int tid = threadIdx.x;
  if (b == 16) {
    if (tid < 128) {
      float s = 0.f;
      for (int j = 0; j < 128; ++j) s += Wp1[(size_t)tid * 256 + j] * b2_fi[j];
      bu_inv[tid] = s;
    } else {
      const int o = tid - 128;
      float s = bp1[o];
      for (int j = 0; j < 128; ++j) s += Wp1[(size_t)o * 256 + 128 + j] * b2_if[j];
      bu_fund[o] = s;
    }
    return;
  }
  const int m = b >> 2;
  const int rb = (b & 3) * 32;
  const float* A = Wp1 + (m >= 2 ? 128 : 0);
  const float* B = (m == 0) ? W2l_fi : (m == 1) ? W2r_fi : (m == 2) ? W2l_if : W2r_if;
  __shared__ float sA[32][132];
  for (int i = tid; i < 32 * 128; i += 256) {
    const int r = i >> 7, c = i & 127;
    sA[r][c] = A[(size_t)(rb + r) * 256 + c];
  }
  __syncthreads();
  const int lr = tid >> 3;
  const int k0 = (tid & 7) * 16;
  float acc[16];
#pragma unroll
  for (int i = 0; i < 16; ++i) acc[i] = 0.f;
  for (int j = 0; j < 128; ++j) {
    const float a = sA[lr][j];
    const float* Brow = B + (size_t)j * 128 + k0;
#pragma unroll
    for (int i = 0; i < 16; i += 4) {
      float4 v = *(const float4*)(Brow + i);
      acc[i] += a * v.x; acc[i + 1] += a * v.y; acc[i + 2] += a * v.z; acc[i + 3] += a * v.w;
    }
  }
  ushort* dst = cw + (size_t)m * 16384 + (size_t)(rb + lr) * 128 + k0;
  ushort ov[16];
#pragma unroll
  for (int i = 0; i < 16; ++i) ov[i] = f2bf(acc[i]);
#pragma unroll
  for (int i = 0; i < 16; i += 4)
    *(ushort4*)(dst + i) = *(const ushort4*)(ov + i);
}

// ---------- CSR construction (both relations fused per stage) ----------

__global__ void count_deg2(const int* __restrict__ d0, int* __restrict__ g0,
                           const int* __restrict__ d1, int* __restrict__ g1, int n) {
  int e = blockIdx.x * blockDim.x + threadIdx.x;
  if (e < n) atomicAdd(&g0[d0[e]], 1);
  else if (e < 2 * n) atomicAdd(&g1[d1[e - n]], 1);
}

__device__ __forceinline__ void scan_partial_body(const int* __restrict__ deg,
                                                  int* __restrict__ bsum, int n, int blk) {
  __shared__ int red[256];
  const int tid = threadIdx.x;
  const int base = blk * 1024 + tid * 4;
  int s = 0;
  if (base + 3 < n) {
    int4 v = *(const int4*)(deg + base);
    s = v.x + v.y + v.z + v.w;
  } else {
    for (int i = 0; i < 4; ++i)
      if (base + i < n) s += deg[base + i];
  }
  red[tid] = s;
  __syncthreads();
  for (int d = 128; d > 0; d >>= 1) {
    if (tid < d) red[tid] += red[tid + d];
    __syncthreads();
  }
  if (tid == 0) bsum[blk] = red[0];
}

__global__ void scan_partial2(const int* __restrict__ degF, int* __restrict__ bsumF, int nF, int nbF,
                              const int* __restrict__ degI, int* __restrict__ bsumI, int nI) {
  if ((int)blockIdx.x < nbF) scan_partial_body(degF, bsumF, nF, blockIdx.x);
  else scan_partial_body(degI, bsumI, nI, blockIdx.x - nbF);
}

__device__ __forceinline__ void scan_small_body(int* __restrict__ bsum, int nb) {
  __shared__ int sh[1024];
  const int tid = threadIdx.x;
  const int v = (tid < nb) ? bsum[tid] : 0;
  sh[tid] = v;
  __syncthreads();
  for (int d = 1; d < 1024; d <<= 1) {
    int t = (tid >= d) ? sh[tid - d] : 0;
    __syncthreads();
    sh[tid] += t;
    __syncthreads();
  }
  if (tid < nb) bsum[tid] = sh[tid] - v;
}

__global__ void scan_small2(int* __restrict__ bsumF, int nbF, int* __restrict__ bsumI, int nbI) {
  if (blockIdx.x == 0) scan_small_body(bsumF, nbF);
  else scan_small_body(bsumI, nbI);
}

__device__ __forceinline__ void scan_apply_body(const int* __restrict__ deg,
                                                const int* __restrict__ bsum,
                                                int* __restrict__ off, int* __restrict__ cur,
                                                int n, int blk) {
  __shared__ int red[256];
  const int tid = threadIdx.x;
  const int base = blk * 1024 + tid * 4;
  int v[4] = {0, 0, 0, 0};
  const bool full = (base + 3 < n);
  if (full) {
    int4 t = *(const int4*)(deg + base);
    v[0] = t.x; v[1] = t.y; v[2] = t.z; v[3] = t.w;
  } else {
    for (int i = 0; i < 4; ++i)
      if (base + i < n) v[i] = deg[base + i];
  }
  const int s = v[0] + v[1] + v[2] + v[3];
  red[tid] = s;
  __syncthreads();
  for (int d = 1; d < 256; d <<= 1) {
    int t = (tid >= d) ? red[tid - d] : 0;
    __syncthreads();
    red[tid] += t;
    __syncthreads();
  }
  int o[4];
  o[0] = bsum[blk] + red[tid] - s;
  o[1] = o[0] + v[0];
  o[2] = o[1] + v[1];
  o[3] = o[2] + v[2];
  if (full) {
    *(int4*)(off + base) = make_int4(o[0], o[1], o[2], o[3]);
    *(int4*)(cur + base) = make_int4(o[0], o[1], o[2], o[3]);
  } else {
    for (int i = 0; i < 4; ++i)
      if (base + i < n) { off[base + i] = o[i]; cur[base + i] = o[i]; }
  }
#pragma unroll
  for (int i = 0; i < 4; ++i)
    if (base + i == n - 1) off[n] = o[i] + v[i];
}

__global__ void scan_apply2(const int* __restrict__ degF, const int* __restrict__ bsumF,
                            int* __restrict__ offF, int* __restrict__ curF, int nF, int nbF,
                            const int* __restrict__ degI, const int* __restrict__ bsumI,
                            int* __restrict__ offI, int* __restrict__ curI, int nI) {
  if ((int)blockIdx.x < nbF) scan_apply_body(degF, bsumF, offF, curF, nF, blockIdx.x);
  else scan_apply_body(degI, bsumI, offI, curI, nI, blockIdx.x - nbF);
}

__global__ void fill_csr2(const int* __restrict__ s0, const int* __restrict__ d0,
                          int* __restrict__ c0, int* __restrict__ r0,
                          const int* __restrict__ s1, const int* __restrict__ d1,
                          int* __restrict__ c1, int* __restrict__ r1, int n) {
  int e = blockIdx.x * blockDim.x + threadIdx.x;
  if (e < n) {
    int pos = atomicAdd(&c0[d0[e]], 1);
    r0[pos] = s0[e];
  } else if (e < 2 * n) {
    int ee = e - n;
    int pos = atomicAdd(&c1[d1[ee]], 1);
    r1[pos] = s1[ee];
  }
}

// ---------- mean aggregation: 16B/lane quad/octet decomposition, 16 rows in flight ----------

__device__ __forceinline__ void acc8(float* a, uint4 u) {
  a[0] += bf_lo(u.x); a[1] += bf_hi(u.x);
  a[2] += bf_lo(u.y); a[3] += bf_hi(u.y);
  a[4] += bf_lo(u.z); a[5] += bf_hi(u.z);
  a[6] += bf_lo(u.w); a[7] += bf_hi(u.w);
}

template <int D>
__device__ __forceinline__ void mean_node(const ushort* __restrict__ xsrc,
                                          const int* __restrict__ csr,
                                          const int* __restrict__ off,
                                          ushort* __restrict__ mean, int node, int lane) {
  const int lo = off[node], hi = off[node + 1];
  float a[8] = {0.f, 0.f, 0.f, 0.f, 0.f, 0.f, 0.f, 0.f};
  if (D == 128) {
    const int q = lane >> 4, l16 = lane & 15;
    const size_t co = (size_t)l16 * 8;
    int e = lo + q;
    for (; e + 12 < hi; e += 16) {
      const int s0 = csr[e], s1 = csr[e + 4], s2 = csr[e + 8], s3 = csr[e + 12];
      uint4 u0 = *(const uint4*)(xsrc + (size_t)s0 * D + co);
      uint4 u1 = *(const uint4*)(xsrc + (size_t)s1 * D + co);
      uint4 u2 = *(const uint4*)(xsrc + (size_t)s2 * D + co);
      uint4 u3 = *(const uint4*)(xsrc + (size_t)s3 * D + co);
      acc8(a, u0); acc8(a, u1); acc8(a, u2); acc8(a, u3);
    }
    for (; e < hi; e += 4) {
      uint4 u = *(const uint4*)(xsrc + (size_t)csr[e] * D + co);
      acc8(a, u);
    }
#pragma unroll
    for (int i = 0; i < 8; ++i) {
      a[i] += __shfl_xor(a[i], 16);
      a[i] += __shfl_xor(a[i], 32);
    }
    if (q == 0) {
      const float sc = (hi > lo) ? 1.0f / (float)(hi - lo) : 0.0f;
      ushort o8[8];
#pragma unroll
      for (int i = 0; i < 8; ++i) o8[i] = f2bf(a[i] * sc);
      *(uint4*)(mean + (size_t)node * D + co) = *(const uint4*)o8;
    }
  } else {  // D == 64: octets of 8 lanes, 16B/lane
    const int oc = lane >> 3, l8 = lane & 7;
    const size_t co = (size_t)l8 * 8;
    int e = lo + oc;
    for (; e + 8 < hi; e += 16) {
      const int s0 = csr[e], s1 = csr[e + 8];
      uint4 u0 = *(const uint4*)(xsrc + (size_t)s0 * D + co);
      uint4 u1 = *(const uint4*)(xsrc + (size_t)s1 * D + co);
      acc8(a, u0); acc8(a, u1);
    }
    for (; e < hi; e += 8) {
      uint4 u = *(const uint4*)(xsrc + (size_t)csr[e] * D + co);
      acc8(a, u);
    }
#pragma unroll
    for (int i = 0; i < 8; ++i) {
      a[i] += __shfl_xor(a[i], 8);
      a[i] += __shfl_xor(a[i], 16);
      a[i] += __shfl_xor(a[i], 32);
    }
    if (oc == 0) {
      const float sc = (hi > lo) ? 1.0f / (float)(hi - lo) : 0.0f;
      ushort o8[8];
#pragma unroll
      for (int i = 0; i < 8; ++i) o8[i] = f2bf(a[i] * sc);
      *(uint4*)(mean + (size_t)node * D + co) = *(const uint4*)o8;
    }
  }
}

// fused: waves [0,nA) -> relation A, [nA, nA+nB) -> relation B
template <int DA, int DB>
__global__ void sage_mean_dual(const ushort* __restrict__ xA, const int* __restrict__ csrA,
                               const int* __restrict__ offA, ushort* __restrict__ outA, int nA,
                               const ushort* __restrict__ xB, const int* __restrict__ csrB,
                               const int* __restrict__ offB, ushort* __restrict__ outB, int nB) {
  const int wave = (int)((blockIdx.x * blockDim.x + threadIdx.x) >> 6);
  const int lane = threadIdx.x & 63;
  if (wave < nA) mean_node<DA>(xA, csrA, offA, outA, wave, lane);
  else if (wave < nA + nB) mean_node<DB>(xB, csrB, offB, outB, wave - nA, lane);
}

// ---------- MFMA GEMM body: out[n,128] = act(A1@W1^T + A2@W2^T + bias) ----------

template <int D1, int D2>
__device__ void gemm_body(const ushort* __restrict__ A1, const ushort* __restrict__ A2,
                          const ushort* __restrict__ W1, const ushort* __restrict__ W2,
                          const float* __restrict__ bias, int act,
                          ushort* __restrict__ out, int n, int blk, ushort* lds) {
  constexpr int K1 = D1 / 32;
  constexpr int K2 = D2 / 32;
  constexpr int CH1 = 128 * D1 / 8;
  constexpr int CHT = 128 * (D1 + D2) / 8;

  const int tid = threadIdx.x;
  const int wid = tid >> 6;
  const int lane = tid & 63;
  const int lo16 = lane & 15;
  const int hi4 = lane >> 4;
  const int row0 = blk * 128 + wid * 32;

  const int r0 = min(row0 + lo16, n - 1);
  const int r1 = min(row0 + 16 + lo16, n - 1);

  bf16x8 aA[2][K1], aB[2][K2];
  {
    const ushort* a0p = A1 + (size_t)r0 * D1 + hi4 * 8;
    const ushort* a1p = A1 + (size_t)r1 * D1 + hi4 * 8;
#pragma unroll
    for (int k = 0; k < K1; ++k) {
      aA[0][k] = *(const bf16x8*)(a0p + k * 32);
      aA[1][k] = *(const bf16x8*)(a1p + k * 32);
    }
    const ushort* b0p = A2 + (size_t)r0 * D2 + hi4 * 8;
    const ushort* b1p = A2 + (size_t)r1 * D2 + hi4 * 8;
#pragma unroll
    for (int k = 0; k < K2; ++k) {
      aB[0][k] = *(const bf16x8*)(b0p + k * 32);
      aB[1][k] = *(const bf16x8*)(b1p + k * 32);
    }
  }

#pragma unroll
  for (int it = 0; it < CHT / 256; ++it) {
    const int c = it * 256 + tid;
    const int g = c * 8;
    bf16x8 v;
    int dest;
    if (g < 128 * D1) {
      const int row = g / D1, col = g % D1;
      v = *(const bf16x8*)(W1 + g);
      dest = ((col >> 5) * 8 + (row >> 4)) * 64 + (((col >> 3) & 3) << 4) + (row & 15);
    } else {
      const int g2 = g - 128 * D1;
      const int row = g2 / D2, col = g2 % D2;
      v = *(const bf16x8*)(W2 + g2);
      dest = CH1 + ((col >> 5) * 8 + (row >> 4)) * 64 + (((col >> 3) & 3) << 4) + (row & 15);
    }
    *((bf16x8*)lds + dest) = v;
  }
  __syncthreads();

  f32x4 acc[2][8];
#pragma unroll
  for (int rt = 0; rt < 2; ++rt)
#pragma unroll
    for (int ct = 0; ct < 8; ++ct)
      acc[rt][ct] = (f32x4){0.f, 0.f, 0.f, 0.f};

  const bf16x8* fr = (const bf16x8*)lds;
#pragma unroll
  for (int k = 0; k < K1; ++k) {
#pragma unroll
    for (int ct = 0; ct < 8; ++ct) {
      bf16x8 w = fr[(k * 8 + ct) * 64 + lane];
      acc[0][ct] = __builtin_amdgcn_mfma_f32_16x16x32_bf16(w, aA[0][k], acc[0][ct], 0, 0, 0);
      acc[1][ct] = __builtin_amdgcn_mfma_f32_16x16x32_bf16(w, aA[1][k], acc[1][ct], 0, 0, 0);
    }
  }
#pragma unroll
  for (int k = 0; k < K2; ++k) {
#pragma unroll
    for (int ct = 0; ct < 8; ++ct) {
      bf16x8 w = fr[CH1 + (k * 8 + ct) * 64 + lane];
      acc[0][ct] = __builtin_amdgcn_mfma_f32_16x16x32_bf16(w, aB[0][k], acc[0][ct], 0, 0, 0);
      acc[1][ct] = __builtin_amdgcn_mfma_f32_16x16x32_bf16(w, aB[1][k], acc[1][ct], 0, 0, 0);
    }
  }

  const int colb = hi4 * 4;
#pragma unroll
  for (int rt = 0; rt < 2; ++rt) {
    const int row = row0 + rt * 16 + lo16;
    if (row < n) {
#pragma unroll
      for (int ct = 0; ct < 8; ++ct) {
        float b4[4];
        *(float4*)b4 = *(const float4*)(bias + ct * 16 + colb);
        ushort o[4];
#pragma unroll
        for (int j = 0; j < 4; ++j) {
          float x = acc[rt][ct][j] + b4[j];
          if (act) x = fmaxf(x, 0.f);
          o[j] = f2bf(x);
        }
        *(ushort4*)(out + (size_t)row * kH + ct * 16 + colb) = *(const ushort4*)o;
      }
    }
  }
}

// layer 1 fused: blocks [0,nbf) fund <128,64>, rest inv <64,128>  (both 48KB LDS)
__global__ __launch_bounds__(256) void gemm_stage1(
    const ushort* A1f, const ushort* A2f, const ushort* W1f, const ushort* W2f,
    const float* biasf, ushort* outf, int nf, int nbf,
    const ushort* A1i, const ushort* A2i, const ushort* W1i, const ushort* W2i,
    const float* biasi, ushort* outi, int ni) {
  __shared__ ushort lds[128 * 192];
  if ((int)blockIdx.x < nbf)
    gemm_body<128, 64>(A1f, A2f, W1f, W2f, biasf, 1, outf, nf, blockIdx.x, lds);
  else
    gemm_body<64, 128>(A1i, A2i, W1i, W2i, biasi, 1, outi, ni, blockIdx.x - nbf, lds);
}

// layer 2 fused (composite weights): both <128,128>, 64KB LDS
__global__ __launch_bounds__(256) void gemm_stage2(
    const ushort* A1f, const ushort* A2f, const ushort* W1f, const ushort* W2f,
    const float* biasf, ushort* outf, int nf, int nbf,
    const ushort* A1i, const ushort* A2i, const ushort* W1i, const ushort* W2i,
    const float* biasi, ushort* outi, int ni) {
  __shared__ ushort lds[128 * 256];
  if ((int)blockIdx.x < nbf)
    gemm_body<128, 128>(A1f, A2f, W1f, W2f, biasf, 0, outf, nf, blockIdx.x, lds);
  else
    gemm_body<128, 128>(A1i, A2i, W1i, W2i, biasi, 0, outi, ni, blockIdx.x - nbf, lds);
}

// ---------- link predictor: 4 links per wave (16-lane quads, 16B/lane) ----------

__global__ void link_pred(const ushort* __restrict__ u_inv, const ushort* __restrict__ u_fund,
                          const int* __restrict__ ei, const int* __restrict__ ej,
                          const float* __restrict__ Wp2, const float* __restrict__ bp2,
                          float* __restrict__ out, int nl) {
  const int wave = (int)((blockIdx.x * blockDim.x + threadIdx.x) >> 6);
  const int lane = threadIdx.x & 63;
  const int q = lane >> 4, l16 = lane & 15;
  const int link = wave * 4 + q;
  if (link >= nl) return;
  const int i = ei[link];
  const int j = ej[link];
  uint4 ua = *(const uint4*)(u_inv + (size_t)i * 128 + l16 * 8);
  uint4 ub = *(const uint4*)(u_fund + (size_t)j * 128 + l16 * 8);
  float4 w0 = *(const float4*)(Wp2 + l16 * 8);
  float4 w1 = *(const float4*)(Wp2 + l16 * 8 + 4);
  float p = fmaxf(bf_lo(ua.x) + bf_lo(ub.x), 0.f) * w0.x
          + fmaxf(bf_hi(ua.x) + bf_hi(ub.x), 0.f) * w0.y
          + fmaxf(bf_lo(ua.y) + bf_lo(ub.y), 0.f) * w0.z
          + fmaxf(bf_hi(ua.y) + bf_hi(ub.y), 0.f) * w0.w
          + fmaxf(bf_lo(ua.z) + bf_lo(ub.z), 0.f) * w1.x
          + fmaxf(bf_hi(ua.z) + bf_hi(ub.z), 0.f) * w1.y
          + fmaxf(bf_lo(ua.w) + bf_lo(ub.w), 0.f) * w1.z
          + fmaxf(bf_hi(ua.w) + bf_hi(ub.w), 0.f) * w1.w;
#pragma unroll
  for (int o = 8; o > 0; o >>= 1) p += __shfl_xor(p, o);
  if (l16 == 0) out[link] = 1.0f / (1.0f + expf(-(p + bp2[0])));
}

}  // namespace

extern "C" void kernel_launch(void* const* d_in, const int* in_sizes, int n_in,
                              void* d_out, int out_size, void* d_ws, size_t ws_size,
                              hipStream_t stream) {
  const float* x_inv  = (const float*)d_in[0];
  const float* x_fund = (const float*)d_in[1];
  const int* src_if   = (const int*)d_in[2];
  const int* dst_if   = (const int*)d_in[3];
  const int* src_fi   = (const int*)d_in[4];
  const int* dst_fi   = (const int*)d_in[5];
  const int* eli_inv  = (const int*)d_in[6];
  const int* eli_fund = (const int*)d_in[7];
  const float* W1l_if = (const float*)d_in[8];
  const float* b1_if  = (const float*)d_in[9];
  const float* W1r_if = (const float*)d_in[10];
  const float* W1l_fi = (const float*)d_in[11];
  const float* b1_fi  = (const float*)d_in[12];
  const float* W1r_fi = (const float*)d_in[13];
  const float* W2l_if = (const float*)d_in[14];
  const float* b2_if  = (const float*)d_in[15];
  const float* W2r_if = (const float*)d_in[16];
  const float* W2l_fi = (const float*)d_in[17];
  const float* b2_fi  = (const float*)d_in[18];
  const float* W2r_fi = (const float*)d_in[19];
  const float* Wp1    = (const float*)d_in[20];
  const float* bp1    = (const float*)d_in[21];
  const float* Wp2    = (const float*)d_in[22];
  const float* bp2    = (const float*)d_in[23];
  float* out = (float*)d_out;

  char* p = (char*)d_ws;
  auto alloc = [&](size_t bytes) -> void* {
    void* r = (void*)p;
    p += (bytes + 255) & ~(size_t)255;
    return r;
  };
  int* deg_fund = (int*)alloc((size_t)kNFund * 4);
  int* deg_inv  = (int*)alloc((size_t)kNInv * 4);
  int* off_fund = (int*)alloc((size_t)(kNFund + 1) * 4);
  int* off_inv  = (int*)alloc((size_t)(kNInv + 1) * 4);
  int* cur_fund = (int*)alloc((size_t)kNFund * 4);
  int* cur_inv  = (int*)alloc((size_t)kNInv * 4);
  int* bsum_fund = (int*)alloc((size_t)1024 * 4);
  int* bsum_inv  = (int*)alloc((size_t)1024 * 4);
  int* csr_if   = (int*)alloc((size_t)kE * 4);
  int* csr_fi   = (int*)alloc((size_t)kE * 4);
  ushort* xi_b = (ushort*)alloc((size_t)kNInv * 128 * 2);
  ushort* xf_b = (ushort*)alloc((size_t)kNFund * 64 * 2);
  ushort* wa   = (ushort*)alloc((size_t)kWTot * 2);
  ushort* cw   = (ushort*)alloc((size_t)4 * 16384 * 2);
  float* bu_inv  = (float*)alloc((size_t)128 * 4);
  float* bu_fund = (float*)alloc((size_t)128 * 4);
  ushort* bufA = (ushort*)alloc((size_t)kNFund * 128 * 2);  // mean_fund
  ushort* bufB = (ushort*)alloc((size_t)kNFund * 128 * 2);  // h_fund
  ushort* bufC = (ushort*)alloc((size_t)kNInv * 128 * 2);   // mean_inv
  ushort* bufD = (ushort*)alloc((size_t)kNInv * 128 * 2);   // h_inv
  ushort* bufE = (ushort*)alloc((size_t)kNFund * 128 * 2);  // u_fund
  ushort* bufF = (ushort*)alloc((size_t)kNInv * 128 * 2);   // u_inv

  const int TB = 256;
  const int nbFund = (kNFund + 1023) / 1024;  // 20
  const int nbInv  = (kNInv + 1023) / 1024;   // 98
  const int gemmF = (kNFund + 127) / 128;     // 157
  const int gemmI = (kNInv + 127) / 128;      // 782

  convert_all<<<(kTotQ2 + TB - 1) / TB, TB, 0, stream>>>(
      x_inv, x_fund, W1l_if, W1r_if, W1l_fi, W1r_fi, xi_b, xf_b, wa, deg_fund, deg_inv);
  make_composite<<<17, 256, 0, stream>>>(Wp1, W2l_fi, W2r_fi, W2l_if, W2r_if,
                                         b2_fi, b2_if, bp1, cw, bu_inv, bu_fund);

  count_deg2<<<(2 * kE + TB - 1) / TB, TB, 0, stream>>>(dst_if, deg_fund, dst_fi, deg_inv, kE);
  scan_partial2<<<nbFund + nbInv, 256, 0, stream>>>(deg_fund, bsum_fund, kNFund, nbFund,
                                                    deg_inv, bsum_inv, kNInv);
  scan_small2<<<2, 1024, 0, stream>>>(bsum_fund, nbFund, bsum_inv, nbInv);
  scan_apply2<<<nbFund + nbInv, 256, 0, stream>>>(deg_fund, bsum_fund, off_fund, cur_fund,
                                                  kNFund, nbFund,
                                                  deg_inv, bsum_inv, off_inv, cur_inv, kNInv);
  fill_csr2<<<(2 * kE + TB - 1) / TB, TB, 0, stream>>>(src_if, dst_if, cur_fund, csr_if,
                                                       src_fi, dst_fi, cur_inv, csr_fi, kE);

  const int meanBlocks = (kNFund + kNInv + 3) / 4;  // 30000

  // ---- layer 1 ----
  sage_mean_dual<128, 64><<<meanBlocks, 256, 0, stream>>>(
      xi_b, csr_if, off_fund, bufA, kNFund, xf_b, csr_fi, off_inv, bufC, kNInv);
  gemm_stage1<<<gemmF + gemmI, 256, 0, stream>>>(
      bufA, xf_b, wa + kW1lIF, wa + kW1rIF, b1_if, bufB, kNFund, gemmF,
      bufC, xi_b, wa + kW1lFI, wa + kW1rFI, b1_fi, bufD, kNInv);
  // ---- layer 2 folded with predictor precompute ----
  sage_mean_dual<128, 128><<<meanBlocks, 256, 0, stream>>>(
      bufD, csr_if, off_fund, bufA, kNFund, bufB, csr_fi, off_inv, bufC, kNInv);
  gemm_stage2<<<gemmF + gemmI, 256, 0, stream>>>(
      bufA, bufB, cw + kCW2lIF, cw + kCW2rIF, bu_fund, bufE, kNFund, gemmF,
      bufC, bufD, cw + kCW2lFI, cw + kCW2rFI, bu_inv, bufF, kNInv);
  // ---- per-link ----
  link_pred<<<(kEL / 4 + 3) / 4, 256, 0, stream>>>(bufF, bufE, eli_inv, eli_fund,
                                                   Wp2, bp2, out, kEL);
}